// Round 12
// baseline (150.126 us; speedup 1.0000x reference)
//
#include <hip/hip_runtime.h>
#include <cmath>
#include <cstdint>

#define TNUM 512
#define HID 2048
#define NEXP 256
#define NGRP 8
#define KTOP 6
#define IDIM 1408
#define RNK 128
#define NPAIR (TNUM*KTOP)          // 3072
#define NRCAP 3328                 // 3072 + 8*32 padding capacity
#define MAXTILES (NRCAP/32)        // 104

typedef _Float16 f16;
typedef f16  f16x8 __attribute__((ext_vector_type(8)));
typedef f16  f16x4 __attribute__((ext_vector_type(4)));
typedef float f32x4 __attribute__((ext_vector_type(4)));
#define MFMA16(a,b,c) __builtin_amdgcn_mfma_f32_16x16x32_f16((a),(b),(c),0,0,0)

static __device__ __forceinline__ float4 ld4(const float* p){ return *reinterpret_cast<const float4*>(p); }
static __device__ __forceinline__ void st4(float* p, float4 v){ *reinterpret_cast<float4*>(p) = v; }
static __device__ __forceinline__ f16x8 ldh8(const f16* p){ return *reinterpret_cast<const f16x8*>(p); }

// ---------------- workspace layout (~35 MB with overlays) ----------------
constexpr size_t A256(size_t x){ return (x + 255) & ~(size_t)255; }
constexpr size_t OFF_SEL    = 0;
constexpr size_t OFF_WT     = A256(OFF_SEL    + (size_t)NPAIR*4);
constexpr size_t OFF_CNT    = A256(OFF_WT     + (size_t)NPAIR*4);
constexpr size_t OFF_ESTART = A256(OFF_CNT    + (size_t)NEXP*4);
constexpr size_t OFF_TG     = A256(OFF_ESTART + (size_t)NEXP*4);
constexpr size_t OFF_HDR    = A256(OFF_TG     + (size_t)MAXTILES*4);
constexpr size_t OFF_DONE   = A256(OFF_HDR    + 16);
constexpr size_t OFF_ROWT   = A256(OFF_DONE   + 16);
constexpr size_t OFF_POS    = A256(OFF_ROWT   + (size_t)NRCAP*4);
constexpr size_t OFF_BIG    = A256(OFF_POS    + (size_t)NPAIR*4);

constexpr size_t SZ_XH    = (size_t)TNUM*HID*2;            // 2 MB
constexpr size_t SZ_UTI   = (size_t)NGRP*RNK*HID*2;        // 4 MB
constexpr size_t SZ_H1ALL = (size_t)2*TNUM*NGRP*RNK*2;     // 2 MB
constexpr size_t SZ_UO    = (size_t)NGRP*IDIM*RNK*2;       // 2.88 MB
constexpr size_t SZ_UOD   = (size_t)NGRP*HID*RNK*2;        // 4 MB
constexpr size_t SZ_WR    = (size_t)NEXP*HID*2;            // 1 MB
constexpr size_t SZ_H2    = (size_t)NRCAP*RNK*2;           // 0.85 MB
constexpr size_t SZ_DOWNO = (size_t)NRCAP*HID*2;           // 13.6 MB (f16)

// overlay region: [xh|xl|utig|utiu|H1] = 14 MB; downo f16 (13.6) overlays it; lpart overlays H1
constexpr size_t OFF_XH    = OFF_BIG;
constexpr size_t OFF_XL    = OFF_XH   + SZ_XH;
constexpr size_t OFF_UTIG  = OFF_XL   + SZ_XH;
constexpr size_t OFF_UTIU  = OFF_UTIG + SZ_UTI;
constexpr size_t OFF_H1    = OFF_UTIU + SZ_UTI;            // f16 [2][T][G*RNK]
constexpr size_t REG_END   = OFF_H1   + SZ_H1ALL;
constexpr size_t OFF_DOWNO = OFF_XH;                       // lives down_out->combine (f16)
constexpr size_t OFF_LPART = OFF_H1;                       // 2 MB, dead before stage1
// persistent tail
constexpr size_t OFF_UOG   = REG_END;
constexpr size_t OFF_UOU   = OFF_UOG  + SZ_UO;
constexpr size_t OFF_UTID  = OFF_UOU  + SZ_UO;
constexpr size_t OFF_UOD   = OFF_UTID + SZ_UO;
constexpr size_t OFF_WRH   = OFF_UOD  + SZ_UOD;
constexpr size_t OFF_WRL   = OFF_WRH  + SZ_WR;
constexpr size_t OFF_H2G   = OFF_WRL  + SZ_WR;
constexpr size_t OFF_H2U   = OFF_H2G  + SZ_H2;
constexpr size_t OFF_D1P   = OFF_H2U  + SZ_H2;             // 4 f16 partial planes
constexpr size_t OFF_D2    = OFF_D1P  + 4*SZ_H2;
constexpr size_t WS_NEED   = OFF_D2   + SZ_H2;             // ~35 MB
static_assert(OFF_DOWNO + SZ_DOWNO <= OFF_UOG, "downo overlay must end before persistent tail");

// ---------------- single merged converter ----------------
// flat grid 12544:
// [0,1024) x hi/lo | [1024,2432) Uog | [2432,3840) Uou | [3840,5888) Uod |
// [5888,6400) wr transpose hi/lo (+cnt/done zero) | [6400,12544) U_in transposes
__global__ __launch_bounds__(256) void k_cvt(
    const float* __restrict__ x,   const float* __restrict__ Uog,
    const float* __restrict__ Uou, const float* __restrict__ Uod,
    const float* __restrict__ wr,
    const float* __restrict__ Uig, const float* __restrict__ Uiu, const float* __restrict__ Uid,
    f16* __restrict__ xh, f16* __restrict__ xl,
    f16* __restrict__ uog, f16* __restrict__ uou, f16* __restrict__ uod,
    f16* __restrict__ wh, f16* __restrict__ wl,
    f16* __restrict__ ig, f16* __restrict__ iu, f16* __restrict__ idn,
    int* __restrict__ cnt, int* __restrict__ done){
  __shared__ float tile[32][33];
  const int b = blockIdx.x, tid = threadIdx.x;
  if(b < 1024){   // x: hi + lo planes (router needs split-f16)
    const size_t i = (size_t)b*256 + tid;
    float4 v = ld4(x + i*4);
    f16x4 H, L;
    H[0]=(f16)v.x; L[0]=(f16)(v.x-(float)H[0]);
    H[1]=(f16)v.y; L[1]=(f16)(v.y-(float)H[1]);
    H[2]=(f16)v.z; L[2]=(f16)(v.z-(float)H[2]);
    H[3]=(f16)v.w; L[3]=(f16)(v.w-(float)H[3]);
    *reinterpret_cast<f16x4*>(xh + i*4) = H;
    *reinterpret_cast<f16x4*>(xl + i*4) = L;
    return;
  }
  if(b < 5888){
    const float* in; f16* hi; size_t i;
    if(b < 2432){        in = Uog; hi = uog; i = (size_t)(b-1024)*256 + tid; }
    else if(b < 3840){   in = Uou; hi = uou; i = (size_t)(b-2432)*256 + tid; }
    else {               in = Uod; hi = uod; i = (size_t)(b-3840)*256 + tid; }
    float4 v = ld4(in + i*4);
    f16x4 H;
    H[0]=(f16)(v.x*16.f); H[1]=(f16)(v.y*16.f); H[2]=(f16)(v.z*16.f); H[3]=(f16)(v.w*16.f);
    *reinterpret_cast<f16x4*>(hi + i*4) = H;
    return;
  }
  if(b < 6400){
    // wr transpose: [2048][256] -> [256][2048] hi/lo (x16). 512 blocks
    const int wb = b - 5888;
    if(wb == 0){ cnt[tid] = 0; if(tid == 0) done[0] = 0; }
    const int c0 = (wb & 7)*32, r0 = (wb >> 3)*32;
    { const int r = tid>>3, c4 = (tid&7)*4;
      float4 v = ld4(wr + (size_t)(r0+r)*NEXP + c0 + c4);
      tile[r][c4]=v.x; tile[r][c4+1]=v.y; tile[r][c4+2]=v.z; tile[r][c4+3]=v.w; }
    __syncthreads();
    { const int c = tid>>3, r4 = (tid&7)*4;
      f16x4 H, L;
      #pragma unroll
      for(int k = 0; k < 4; k++){
        float v = tile[r4+k][c]*16.f;
        H[k] = (f16)v; L[k] = (f16)(v - (float)H[k]);
      }
      const size_t o = (size_t)(c0+c)*HID + r0 + r4;
      *reinterpret_cast<f16x4*>(wh + o) = H;
      *reinterpret_cast<f16x4*>(wl + o) = L; }
    return;
  }
  // U_in transposes: [G][R][128] -> [G][128][R] (x16)
  const int b2 = b - 6400;
  const int cx = b2 & 3, ry = (b2>>2) & 63, z = b2 >> 8;
  const int tensor = z >> 3, g = z & 7;
  const float* in; f16* o; int R;
  if(tensor == 0){ in = Uig; o = ig; R = HID; }
  else if(tensor == 1){ in = Uiu; o = iu; R = HID; }
  else { in = Uid; o = idn; R = IDIM; }
  const int r0 = ry*32, c0 = cx*32;
  if(r0 >= R) return;
  in += (size_t)g*R*RNK; o += (size_t)g*RNK*R;
  { const int r = tid>>3, c4 = (tid&7)*4;
    float4 v = ld4(in + (size_t)(r0+r)*RNK + c0 + c4);
    tile[r][c4]=v.x; tile[r][c4+1]=v.y; tile[r][c4+2]=v.z; tile[r][c4+3]=v.w; }
  __syncthreads();
  { const int c = tid>>3, r4 = (tid&7)*4;
    f16x4 H;
    #pragma unroll
    for(int k = 0; k < 4; k++) H[k] = (f16)(tile[r4+k][c]*16.f);
    *reinterpret_cast<f16x4*>(o + (size_t)(c0+c)*R + r0 + r4) = H; }
}

// ---------------- router MFMA, split-f16 3-pass, fp32-class accuracy ----------------
__global__ __launch_bounds__(256) void k_router_mfma(
    const f16* __restrict__ xh, const f16* __restrict__ xl,
    const f16* __restrict__ wh, const f16* __restrict__ wl,
    float* __restrict__ lpart){
  __shared__ float red[4][32][64];
  const int m = blockIdx.x, ecol = blockIdx.y, kz = blockIdx.z;
  const int tid = threadIdx.x;
  const int wid = tid>>6, lane = tid&63, q = lane>>4, id = lane&15;
  const int r0 = m*32, e0 = ecol*64;
  const int kb = kz*512 + wid*128;
  f32x4 acc[2][4];
  #pragma unroll
  for(int f = 0; f < 2; f++)
    #pragma unroll
    for(int c = 0; c < 4; c++) acc[f][c] = (f32x4){0.f,0.f,0.f,0.f};
  #pragma unroll
  for(int kk = 0; kk < 128; kk += 32){
    const size_t a0 = (size_t)(r0+id)*HID    + kb + kk + q*8;
    const size_t a1 = (size_t)(r0+16+id)*HID + kb + kk + q*8;
    f16x8 ah0 = ldh8(xh + a0), al0 = ldh8(xl + a0);
    f16x8 ah1 = ldh8(xh + a1), al1 = ldh8(xl + a1);
    #pragma unroll
    for(int c = 0; c < 4; c++){
      const size_t bo = (size_t)(e0 + c*16 + id)*HID + kb + kk + q*8;
      f16x8 bh = ldh8(wh + bo);
      f16x8 bl = ldh8(wl + bo);
      acc[0][c] = MFMA16(ah0, bh, acc[0][c]);
      acc[0][c] = MFMA16(ah0, bl, acc[0][c]);
      acc[0][c] = MFMA16(al0, bh, acc[0][c]);
      acc[1][c] = MFMA16(ah1, bh, acc[1][c]);
      acc[1][c] = MFMA16(ah1, bl, acc[1][c]);
      acc[1][c] = MFMA16(al1, bh, acc[1][c]);
    }
  }
  #pragma unroll
  for(int f = 0; f < 2; f++)
    #pragma unroll
    for(int c = 0; c < 4; c++)
      #pragma unroll
      for(int r = 0; r < 4; r++)
        red[wid][f*16 + q*4 + r][c*16 + id] = acc[f][c][r];
  __syncthreads();
  const int row = tid>>3, c8 = (tid&7)*8;
  float o[8];
  #pragma unroll
  for(int j = 0; j < 8; j++)
    o[j] = (red[0][row][c8+j] + red[1][row][c8+j] + red[2][row][c8+j] + red[3][row][c8+j])*0.0625f;
  float* dst = &lpart[((size_t)kz*TNUM + r0 + row)*NEXP + e0 + c8];
  st4(dst,     make_float4(o[0],o[1],o[2],o[3]));
  st4(dst + 4, make_float4(o[4],o[5],o[6],o[7]));
}

// ---------------- fused top-6 + meta/scatter (last-block-done pattern) ----------------
__global__ __launch_bounds__(256) void k_topk_meta(
    const float* __restrict__ lpart,
    int* __restrict__ sel, float* __restrict__ wt, int* __restrict__ cnt,
    int* __restrict__ done,
    int* __restrict__ estart, int* __restrict__ tile_group, int* __restrict__ hdr,
    int* __restrict__ row_t, int* __restrict__ pos_of_pair){
  __shared__ float wv[4];
  __shared__ int   wi[4];
  __shared__ float swin[KTOP];
  __shared__ int   iwin[KTOP];
  __shared__ int   lastflag;
  __shared__ int scnt[256];
  __shared__ int gsum[8];
  __shared__ int g0[9];
  __shared__ int curs[256];
  const int t = blockIdx.x, tid = threadIdx.x;
  const int lane = tid & 63, wid = tid >> 6;
  const size_t base = (size_t)t*NEXP + tid;
  float v = lpart[base] + lpart[base + (size_t)TNUM*NEXP]
          + lpart[base + (size_t)2*TNUM*NEXP] + lpart[base + (size_t)3*TNUM*NEXP];
  for(int k = 0; k < KTOP; k++){
    float cv = v; int ci = tid;
    #pragma unroll
    for(int off = 1; off < 64; off <<= 1){
      float ov = __shfl_xor(cv, off);
      int   oi = __shfl_xor(ci, off);
      if(ov > cv || (ov == cv && oi < ci)){ cv = ov; ci = oi; }
    }
    if(lane == 0){ wv[wid] = cv; wi[wid] = ci; }
    __syncthreads();
    if(tid == 0){
      float bv = wv[0]; int bi = wi[0];
      #pragma unroll
      for(int w2 = 1; w2 < 4; w2++)
        if(wv[w2] > bv || (wv[w2] == bv && wi[w2] < bi)){ bv = wv[w2]; bi = wi[w2]; }
      swin[k] = bv; iwin[k] = bi;
    }
    __syncthreads();
    if(tid == iwin[k]) v = -INFINITY;
  }
  if(tid == 0){
    float mx = swin[0], s = 0.f, ww[KTOP];
    #pragma unroll
    for(int k = 0; k < KTOP; k++){ ww[k] = expf(swin[k]-mx); s += ww[k]; }
    float inv = 1.f/s;
    #pragma unroll
    for(int k = 0; k < KTOP; k++){
      sel[t*KTOP+k] = iwin[k];
      wt[t*KTOP+k]  = ww[k]*inv;
      atomicAdd(&cnt[iwin[k]], 1);
    }
    __threadfence();                         // publish sel/wt/cnt at device scope
    const int old = atomicAdd(done, 1);
    lastflag = (old == TNUM-1) ? 1 : 0;
  }
  __syncthreads();
  if(!lastflag) return;
  __threadfence();                           // acquire-side fence before reading others' data
  // ---- meta + scatter (runs in exactly one block; identical result whichever it is) ----
  scnt[tid] = cnt[tid];
  if(tid < 8) gsum[tid] = 0;
  __syncthreads();
  atomicAdd(&gsum[tid>>5], scnt[tid]);
  __syncthreads();
  if(tid == 0){
    int run = 0;
    for(int g = 0; g < 8; g++){ g0[g] = run; run += (gsum[g]+31) & ~31; }
    g0[8] = run; hdr[0] = run>>5; hdr[1] = run;
  }
  __syncthreads();
  int g = tid >> 5, s = g0[g];
  for(int i = (g<<5); i < tid; i++) s += scnt[i];
  estart[tid] = s; curs[tid] = s;
  const int nt = g0[8] >> 5;
  for(int t2 = tid; t2 < MAXTILES; t2 += 256){
    int gg = -1;
    if(t2 < nt){
      for(int g2 = 0; g2 < 8; g2++) if(t2*32 >= g0[g2] && t2*32 < g0[g2+1]) gg = g2;
    }
    tile_group[t2] = gg;
  }
  __syncthreads();
  for(int p = tid; p < NPAIR; p += 256){
    const int e = sel[p];
    const int pos = atomicAdd(&curs[e], 1);
    row_t[pos] = p / KTOP;
    pos_of_pair[p] = pos;
  }
}

// ---------------- stage1 MFMA v4: quarter-col split, grid (64 nt, 16 m), 16 KB LDS ----------------
// nt -> pu=nt>>5, g=(nt>>2)&7, ch=nt&3 (32-col quarter); d%8 = nt%8 keeps B-sharers on one XCD
__global__ __launch_bounds__(256) void k_mm_stage1(
    const f16* __restrict__ xh,
    const f16* __restrict__ Bg_, const f16* __restrict__ Bu_,
    f16* __restrict__ H1){
  __shared__ float red[4][32][32];
  const int nt = blockIdx.x, m = blockIdx.y;
  const int pu = nt>>5, g = (nt>>2)&7, ch = nt&3;
  const f16* B = (pu ? Bu_ : Bg_) + (size_t)g*RNK*HID + (size_t)ch*32*HID;
  const int tid = threadIdx.x;
  const int wid = tid>>6, lane = tid&63, q = lane>>4, id = lane&15;
  const int kb = wid*512;
  const int r0 = m*32;
  f32x4 acc[2][2];
  #pragma unroll
  for(int f = 0; f < 2; f++)
    #pragma unroll
    for(int c = 0; c < 2; c++) acc[f][c] = (f32x4){0.f,0.f,0.f,0.f};
  #pragma unroll 4
  for(int kk = 0; kk < 512; kk += 32){
    f16x8 a0 = ldh8(xh + (size_t)(r0+id)*HID    + kb + kk + q*8);
    f16x8 a1 = ldh8(xh + (size_t)(r0+16+id)*HID + kb + kk + q*8);
    #pragma unroll
    for(int c = 0; c < 2; c++){
      f16x8 b = ldh8(B + (size_t)(c*16+id)*HID + kb + kk + q*8);
      acc[0][c] = MFMA16(a0, b, acc[0][c]);
      acc[1][c] = MFMA16(a1, b, acc[1][c]);
    }
  }
  #pragma unroll
  for(int f = 0; f < 2; f++)
    #pragma unroll
    for(int c = 0; c < 2; c++)
      #pragma unroll
      for(int r = 0; r < 4; r++)
        red[wid][f*16 + q*4 + r][c*16 + id] = acc[f][c][r];
  __syncthreads();
  f16* out = H1 + (size_t)pu*TNUM*(NGRP*RNK);
  const int row = tid>>3, c4 = (tid&7)*4;
  f16x4 o4;
  #pragma unroll
  for(int j = 0; j < 4; j++)
    o4[j] = (f16)(red[0][row][c4+j] + red[1][row][c4+j] + red[2][row][c4+j] + red[3][row][c4+j]);
  *reinterpret_cast<f16x4*>(&out[(size_t)(r0+row)*(NGRP*RNK) + g*RNK + ch*32 + c4]) = o4;
}

// ---------------- core2 MFMA with in-kernel fp32->f16 transpose of the core ----------------
__global__ __launch_bounds__(256) void k_core2(
    const float* __restrict__ Cg, const float* __restrict__ Cu,
    const f16* __restrict__ H1,
    const int* __restrict__ estart, const int* __restrict__ cnt,
    const int* __restrict__ row_t,
    f16* __restrict__ h2g, f16* __restrict__ h2u){
  __shared__ f16 Cs[RNK][RNK+8];
  __shared__ float tile[32][33];
  const int e = blockIdx.x, up = blockIdx.y;
  const int n = cnt[e];
  if(n == 0) return;
  const float* Cf = (up ? Cu : Cg) + (size_t)e*RNK*RNK;
  const int tid = threadIdx.x;
  #pragma unroll 2
  for(int st = 0; st < 16; st++){
    const int R0 = (st>>2)*32, C0 = (st&3)*32;
    { const int r = tid>>3, c4 = (tid&7)*4;
      float4 v = ld4(Cf + (size_t)(R0+r)*RNK + C0 + c4);
      tile[r][c4]=v.x; tile[r][c4+1]=v.y; tile[r][c4+2]=v.z; tile[r][c4+3]=v.w; }
    __syncthreads();
    { const int c = tid>>3, r4 = (tid&7)*4;
      f16x4 H;
      #pragma unroll
      for(int k2 = 0; k2 < 4; k2++) H[k2] = (f16)(tile[r4+k2][c]*16.f);
      *reinterpret_cast<f16x4*>(&Cs[C0+c][R0+r4]) = H; }
    __syncthreads();
  }
  const int j0 = estart[e], g = e >> 5;
  const f16* A = H1 + (size_t)up*TNUM*(NGRP*RNK);
  f16* o = up ? h2u : h2g;
  const int wid = tid>>6, lane = tid&63, q = lane>>4, id = lane&15;
  for(int rt = 0; rt*16 < n; rt++){
    const int jrow = j0 + rt*16 + id;
    const int jj = jrow < j0+n ? jrow : j0;
    const f16* arow = A + (size_t)row_t[jj]*(NGRP*RNK) + g*RNK;
    f32x4 acc0 = (f32x4){0.f,0.f,0.f,0.f};
    f32x4 acc1 = (f32x4){0.f,0.f,0.f,0.f};
    #pragma unroll
    for(int kk = 0; kk < RNK; kk += 32){
      f16x8 a = ldh8(arow + kk + q*8);
      f16x8 b0 = *reinterpret_cast<const f16x8*>(&Cs[wid*32 + id][kk + q*8]);
      f16x8 b1 = *reinterpret_cast<const f16x8*>(&Cs[wid*32 + 16 + id][kk + q*8]);
      acc0 = MFMA16(a, b0, acc0);
      acc1 = MFMA16(a, b1, acc1);
    }
    #pragma unroll
    for(int r = 0; r < 4; r++){
      const int j = j0 + rt*16 + q*4 + r;
      if(j < j0+n){
        o[(size_t)j*RNK + wid*32 + id]      = (f16)acc0[r];
        o[(size_t)j*RNK + wid*32 + 16 + id] = (f16)acc1[r];
      }
    }
  }
}

// ---------------- fused gateup + down_in ----------------
// grid (MAXTILES, 4 K-quarters); block: 32 rows, 352 inter cols in LDS, then d1 partial
__global__ __launch_bounds__(256) void k_gateup_downin(
    const f16* __restrict__ Ag, const f16* __restrict__ Au,
    const f16* __restrict__ Bg, const f16* __restrict__ Bu,
    const f16* __restrict__ Bd,
    const int* __restrict__ tg,
    f16* __restrict__ d1p){
  __shared__ f16 inter_s[32][360];   // 352 cols + 8 pad (stride 720 B, 16B-aligned)
  const int g = tg[blockIdx.x];
  if(g < 0) return;
  const int j0 = blockIdx.x*32, qz = blockIdx.y;
  const int cbase = qz*352;
  const int tid = threadIdx.x, wid = tid>>6, lane = tid&63, q = lane>>4, id = lane&15;
  const size_t bbase = (size_t)g*IDIM*RNK;
  // hoist A fragments (h2 rows j0..j0+31, full K=128, both planes) -> 16 f16x8 regs
  f16x8 aG[2][4], aU[2][4];
  #pragma unroll
  for(int f = 0; f < 2; f++)
    #pragma unroll
    for(int k4 = 0; k4 < 4; k4++){
      const size_t off = (size_t)(j0 + f*16 + id)*RNK + k4*32 + q*8;
      aG[f][k4] = ldh8(Ag + off);
      aU[f][k4] = ldh8(Au + off);
    }
  // phase 1: inter_s = silu(gate)*up for cols [cbase, cbase+352)
  for(int t = wid; t < 22; t += 4){
    const int c0 = cbase + t*16;
    f32x4 accg0 = (f32x4){0.f,0.f,0.f,0.f}, accg1 = (f32x4){0.f,0.f,0.f,0.f};
    f32x4 accu0 = (f32x4){0.f,0.f,0.f,0.f}, accu1 = (f32x4){0.f,0.f,0.f,0.f};
    #pragma unroll
    for(int k4 = 0; k4 < 4; k4++){
      const size_t bo = bbase + (size_t)(c0 + id)*RNK + k4*32 + q*8;
      f16x8 bg = ldh8(Bg + bo);
      f16x8 bu = ldh8(Bu + bo);
      accg0 = MFMA16(aG[0][k4], bg, accg0);
      accg1 = MFMA16(aG[1][k4], bg, accg1);
      accu0 = MFMA16(aU[0][k4], bu, accu0);
      accu1 = MFMA16(aU[1][k4], bu, accu1);
    }
    #pragma unroll
    for(int r = 0; r < 4; r++){
      float vg0 = accg0[r]*(1.f/4096.f), vu0 = accu0[r]*(1.f/4096.f);
      float vg1 = accg1[r]*(1.f/4096.f), vu1 = accu1[r]*(1.f/4096.f);
      inter_s[q*4+r][t*16+id]    = (f16)(vg0/(1.f+expf(-vg0))*vu0*256.f);
      inter_s[16+q*4+r][t*16+id] = (f16)(vg1/(1.f+expf(-vg1))*vu1*256.f);
    }
  }
  __syncthreads();
  // phase 2: d1 partial = inter_s @ Bd[K slice]; wave w -> cols [w*32, w*32+32)
  const int col0 = wid*32;
  f32x4 acc[2][2];
  #pragma unroll
  for(int f = 0; f < 2; f++)
    #pragma unroll
    for(int c = 0; c < 2; c++) acc[f][c] = (f32x4){0.f,0.f,0.f,0.f};
  const f16* Bdg = Bd + (size_t)g*RNK*IDIM;
  #pragma unroll 2
  for(int kk = 0; kk < 352; kk += 32){
    f16x8 a0 = *reinterpret_cast<const f16x8*>(&inter_s[id][kk + q*8]);
    f16x8 a1 = *reinterpret_cast<const f16x8*>(&inter_s[16+id][kk + q*8]);
    #pragma unroll
    for(int c = 0; c < 2; c++){
      f16x8 b = ldh8(Bdg + (size_t)(col0 + c*16 + id)*IDIM + cbase + kk + q*8);
      acc[0][c] = MFMA16(a0, b, acc[0][c]);
      acc[1][c] = MFMA16(a1, b, acc[1][c]);
    }
  }
  f16* out = d1p + (size_t)qz*NRCAP*RNK;
  #pragma unroll
  for(int f = 0; f < 2; f++)
    #pragma unroll
    for(int c = 0; c < 2; c++)
      #pragma unroll
      for(int r = 0; r < 4; r++)
        out[(size_t)(j0 + f*16 + q*4 + r)*RNK + col0 + c*16 + id] = (f16)acc[f][c][r];
}

// ---------------- core_down MFMA: sums 4 f16 d1 partials; in-kernel core transpose ----------------
__global__ __launch_bounds__(256) void k_core_down(
    const float* __restrict__ Cd,
    const f16* __restrict__ d1p,
    const int* __restrict__ estart, const int* __restrict__ cnt,
    f16* __restrict__ d2){
  __shared__ f16 Cs[RNK][RNK+8];
  __shared__ float tile[32][33];
  const int e = blockIdx.x;
  const int n = cnt[e];
  if(n == 0) return;
  const float* Cf = Cd + (size_t)e*RNK*RNK;
  const int tid = threadIdx.x;
  #pragma unroll 2
  for(int st = 0; st < 16; st++){
    const int R0 = (st>>2)*32, C0 = (st&3)*32;
    { const int r = tid>>3, c4 = (tid&7)*4;
      float4 v = ld4(Cf + (size_t)(R0+r)*RNK + C0 + c4);
      tile[r][c4]=v.x; tile[r][c4+1]=v.y; tile[r][c4+2]=v.z; tile[r][c4+3]=v.w; }
    __syncthreads();
    { const int c = tid>>3, r4 = (tid&7)*4;
      f16x4 H;
      #pragma unroll
      for(int k2 = 0; k2 < 4; k2++) H[k2] = (f16)(tile[r4+k2][c]*16.f);
      *reinterpret_cast<f16x4*>(&Cs[C0+c][R0+r4]) = H; }
    __syncthreads();
  }
  const int j0 = estart[e];
  const size_t PL = (size_t)NRCAP*RNK;
  const int wid = tid>>6, lane = tid&63, q = lane>>4, id = lane&15;
  for(int rt = 0; rt*16 < n; rt++){
    const int jrow = j0 + rt*16 + id;
    const int jj = jrow < j0+n ? jrow : j0;
    const size_t arow = (size_t)jj*RNK;
    f32x4 acc0 = (f32x4){0.f,0.f,0.f,0.f};
    f32x4 acc1 = (f32x4){0.f,0.f,0.f,0.f};
    #pragma unroll
    for(int kk = 0; kk < RNK; kk += 32){
      const size_t off = arow + kk + q*8;
      f16x8 a = ldh8(d1p + off);
      a += ldh8(d1p + off + PL);
      a += ldh8(d1p + off + 2*PL);
      a += ldh8(d1p + off + 3*PL);
      f16x8 b0 = *reinterpret_cast<const f16x8*>(&Cs[wid*32 + id][kk + q*8]);
      f16x8 b1 = *reinterpret_cast<const f16x8*>(&Cs[wid*32 + 16 + id][kk + q*8]);
      acc0 = MFMA16(a, b0, acc0);
      acc1 = MFMA16(a, b1, acc1);
    }
    #pragma unroll
    for(int r = 0; r < 4; r++){
      const int j = j0 + rt*16 + q*4 + r;
      if(j < j0+n){
        d2[(size_t)j*RNK + wid*32 + id]      = (f16)acc0[r];
        d2[(size_t)j*RNK + wid*32 + 16 + id] = (f16)acc1[r];
      }
    }
  }
}

// ---------------- down_out MFMA: writes f16 downo at x2^10 scale ----------------
__global__ __launch_bounds__(128) void k_mm_down_out(
    const f16* __restrict__ A_, const f16* __restrict__ B_,
    const int* __restrict__ tg,
    f16* __restrict__ downo){
  const int g = tg[blockIdx.x];
  if(g < 0) return;
  const int j0 = blockIdx.x*32;
  const f16* B = B_ + (size_t)g*HID*RNK;
  const int tid = threadIdx.x;
  const int wid = tid>>6, lane = tid&63, q = lane>>4, id = lane&15;
  const int c0 = blockIdx.y*128 + wid*64;
  f32x4 acc[2][4];
  #pragma unroll
  for(int f = 0; f < 2; f++)
    #pragma unroll
    for(int c = 0; c < 4; c++) acc[f][c] = (f32x4){0.f,0.f,0.f,0.f};
  #pragma unroll 2
  for(int kk = 0; kk < RNK; kk += 32){
    f16x8 a0 = ldh8(A_ + (size_t)(j0+id)*RNK    + kk + q*8);
    f16x8 a1 = ldh8(A_ + (size_t)(j0+16+id)*RNK + kk + q*8);
    #pragma unroll
    for(int c = 0; c < 4; c++){
      f16x8 b = ldh8(B + (size_t)(c0 + c*16 + id)*RNK + kk + q*8);
      acc[0][c] = MFMA16(a0, b, acc[0][c]);
      acc[1][c] = MFMA16(a1, b, acc[1][c]);
    }
  }
  #pragma unroll
  for(int f = 0; f < 2; f++)
    #pragma unroll
    for(int c = 0; c < 4; c++)
      #pragma unroll
      for(int r = 0; r < 4; r++)
        downo[(size_t)(j0 + f*16 + q*4 + r)*HID + c0 + c*16 + id] = (f16)(acc[f][c][r]*(1.f/1024.f));
}

// ---------------- combine: out[t] = sum_k wt/1024 * downo16[pos(t,k)] ----------------
__global__ __launch_bounds__(256) void k_combine(const f16* __restrict__ downo,
                                                 const int* __restrict__ pos_of_pair,
                                                 const float* __restrict__ wt,
                                                 float* __restrict__ out){
  const int idx = blockIdx.x*256 + threadIdx.x;      // 0..262143
  const int t  = idx >> 9;
  const int h4 = (idx & 511) << 2;
  float4 acc = make_float4(0.f,0.f,0.f,0.f);
  #pragma unroll
  for(int k = 0; k < KTOP; k++){
    const int p = t*KTOP + k;
    const float w = wt[p]*(1.f/1024.f);
    const int pos = pos_of_pair[p];
    f16x4 v = *reinterpret_cast<const f16x4*>(&downo[(size_t)pos*HID + h4]);
    acc.x += w*(float)v[0]; acc.y += w*(float)v[1];
    acc.z += w*(float)v[2]; acc.w += w*(float)v[3];
  }
  st4(&out[(size_t)t*HID + h4], acc);
}

extern "C" void kernel_launch(void* const* d_in, const int* in_sizes, int n_in,
                              void* d_out, int out_size, void* d_ws, size_t ws_size,
                              hipStream_t stream){
  const float* x   = (const float*)d_in[0];
  const float* wr  = (const float*)d_in[1];
  const float* Uig = (const float*)d_in[2];
  const float* cg  = (const float*)d_in[3];
  const float* Uog = (const float*)d_in[4];
  const float* Uiu = (const float*)d_in[5];
  const float* cu  = (const float*)d_in[6];
  const float* Uou = (const float*)d_in[7];
  const float* Uid = (const float*)d_in[8];
  const float* cd  = (const float*)d_in[9];
  const float* Uod = (const float*)d_in[10];
  float* out = (float*)d_out;
  char* ws = (char*)d_ws;
  if(ws_size < WS_NEED) return;   // insufficient scratch — fail visibly

  int*   sel    = (int*)  (ws + OFF_SEL);
  float* wt     = (float*)(ws + OFF_WT);
  int*   cnt    = (int*)  (ws + OFF_CNT);
  int*   estart = (int*)  (ws + OFF_ESTART);
  int*   tg     = (int*)  (ws + OFF_TG);
  int*   hdr    = (int*)  (ws + OFF_HDR);
  int*   done   = (int*)  (ws + OFF_DONE);
  int*   row_t  = (int*)  (ws + OFF_ROWT);
  int*   pos    = (int*)  (ws + OFF_POS);
  float* lpart  = (float*)(ws + OFF_LPART);
  f16* xh    = (f16*)(ws + OFF_XH);
  f16* xl    = (f16*)(ws + OFF_XL);
  f16* utig  = (f16*)(ws + OFF_UTIG);
  f16* utiu  = (f16*)(ws + OFF_UTIU);
  f16* H1    = (f16*)(ws + OFF_H1);
  f16* uog   = (f16*)(ws + OFF_UOG);
  f16* uou   = (f16*)(ws + OFF_UOU);
  f16* utid  = (f16*)(ws + OFF_UTID);
  f16* uod   = (f16*)(ws + OFF_UOD);
  f16* wrh   = (f16*)(ws + OFF_WRH);
  f16* wrl   = (f16*)(ws + OFF_WRL);
  f16* h2g   = (f16*)(ws + OFF_H2G);
  f16* h2u   = (f16*)(ws + OFF_H2U);
  f16* d1p   = (f16*)(ws + OFF_D1P);
  f16* d2    = (f16*)(ws + OFF_D2);
  f16* downo = (f16*)(ws + OFF_DOWNO);

  // one merged conversion kernel (also zeroes cnt + done)
  k_cvt      <<<12544,             256, 0, stream>>>(x, Uog, Uou, Uod, wr, Uig, Uiu, Uid,
                                                     xh, xl, uog, uou, uod, wrh, wrl,
                                                     utig, utiu, utid, cnt, done);

  // routing chain (lpart overlays H1, dead before stage1)
  k_router_mfma<<<dim3(16,4,4),    256, 0, stream>>>(xh, xl, wrh, wrl, lpart);
  k_topk_meta<<<TNUM,              256, 0, stream>>>(lpart, sel, wt, cnt, done,
                                                     estart, tg, hdr, row_t, pos);

  k_mm_stage1<<<dim3(64,16),       256, 0, stream>>>(xh, utig, utiu, H1);
  k_core2    <<<dim3(NEXP,2),      256, 0, stream>>>(cg, cu, H1, estart, cnt, row_t, h2g, h2u);
  k_gateup_downin<<<dim3(MAXTILES,4),256,0, stream>>>(h2g, h2u, uog, uou, utid, tg, d1p);
  k_core_down<<<NEXP,              256, 0, stream>>>(cd, d1p, estart, cnt, d2);
  k_mm_down_out<<<dim3(MAXTILES,16),128,0, stream>>>(d2, uod, tg, downo);
  k_combine  <<<1024,              256, 0, stream>>>(downo, pos, wt, out);
}

// Round 13
// 143.798 us; speedup vs baseline: 1.0440x; 1.0440x over previous
//
#include <hip/hip_runtime.h>
#include <cmath>
#include <cstdint>

#define TNUM 512
#define HID 2048
#define NEXP 256
#define NGRP 8
#define KTOP 6
#define IDIM 1408
#define RNK 128
#define NPAIR (TNUM*KTOP)          // 3072
#define NRCAP 3328                 // 3072 + 8*32 padding capacity
#define MAXTILES (NRCAP/32)        // 104

typedef _Float16 f16;
typedef f16  f16x8 __attribute__((ext_vector_type(8)));
typedef f16  f16x4 __attribute__((ext_vector_type(4)));
typedef float f32x4 __attribute__((ext_vector_type(4)));
#define MFMA16(a,b,c) __builtin_amdgcn_mfma_f32_16x16x32_f16((a),(b),(c),0,0,0)

static __device__ __forceinline__ float4 ld4(const float* p){ return *reinterpret_cast<const float4*>(p); }
static __device__ __forceinline__ void st4(float* p, float4 v){ *reinterpret_cast<float4*>(p) = v; }
static __device__ __forceinline__ f16x8 ldh8(const f16* p){ return *reinterpret_cast<const f16x8*>(p); }

// ---------------- workspace layout (~35 MB with overlays) ----------------
constexpr size_t A256(size_t x){ return (x + 255) & ~(size_t)255; }
constexpr size_t OFF_SEL    = 0;
constexpr size_t OFF_WT     = A256(OFF_SEL    + (size_t)NPAIR*4);
constexpr size_t OFF_CNT    = A256(OFF_WT     + (size_t)NPAIR*4);
constexpr size_t OFF_ESTART = A256(OFF_CNT    + (size_t)NEXP*4);
constexpr size_t OFF_TG     = A256(OFF_ESTART + (size_t)NEXP*4);
constexpr size_t OFF_HDR    = A256(OFF_TG     + (size_t)MAXTILES*4);
constexpr size_t OFF_DONE   = A256(OFF_HDR    + 16);
constexpr size_t OFF_ROWT   = A256(OFF_DONE   + 16);
constexpr size_t OFF_POS    = A256(OFF_ROWT   + (size_t)NRCAP*4);
constexpr size_t OFF_BIG    = A256(OFF_POS    + (size_t)NPAIR*4);

constexpr size_t SZ_XH    = (size_t)TNUM*HID*2;            // 2 MB
constexpr size_t SZ_UTI   = (size_t)NGRP*RNK*HID*2;        // 4 MB
constexpr size_t SZ_H1ALL = (size_t)2*TNUM*NGRP*RNK*2;     // 2 MB
constexpr size_t SZ_UO    = (size_t)NGRP*IDIM*RNK*2;       // 2.88 MB
constexpr size_t SZ_UOD   = (size_t)NGRP*HID*RNK*2;        // 4 MB
constexpr size_t SZ_WR    = (size_t)NEXP*HID*2;            // 1 MB
constexpr size_t SZ_H2    = (size_t)NRCAP*RNK*2;           // 0.85 MB
constexpr size_t SZ_DOWNO = (size_t)NRCAP*HID*2;           // 13.6 MB (f16)

// overlay region: [xh|xl|utig|utiu|H1] = 14 MB; downo f16 (13.6) overlays it; lpart overlays H1
constexpr size_t OFF_XH    = OFF_BIG;
constexpr size_t OFF_XL    = OFF_XH   + SZ_XH;
constexpr size_t OFF_UTIG  = OFF_XL   + SZ_XH;
constexpr size_t OFF_UTIU  = OFF_UTIG + SZ_UTI;
constexpr size_t OFF_H1    = OFF_UTIU + SZ_UTI;            // f16 [2][T][G*RNK]
constexpr size_t REG_END   = OFF_H1   + SZ_H1ALL;
constexpr size_t OFF_DOWNO = OFF_XH;                       // lives down_out->combine (f16)
constexpr size_t OFF_LPART = OFF_H1;                       // 2 MB, dead before stage1
// persistent tail
constexpr size_t OFF_UOG   = REG_END;
constexpr size_t OFF_UOU   = OFF_UOG  + SZ_UO;
constexpr size_t OFF_UTID  = OFF_UOU  + SZ_UO;
constexpr size_t OFF_UOD   = OFF_UTID + SZ_UO;
constexpr size_t OFF_WRH   = OFF_UOD  + SZ_UOD;
constexpr size_t OFF_WRL   = OFF_WRH  + SZ_WR;
constexpr size_t OFF_H2G   = OFF_WRL  + SZ_WR;
constexpr size_t OFF_H2U   = OFF_H2G  + SZ_H2;
constexpr size_t OFF_D1P   = OFF_H2U  + SZ_H2;             // 4 f16 partial planes
constexpr size_t OFF_D2    = OFF_D1P  + 4*SZ_H2;
constexpr size_t WS_NEED   = OFF_D2   + SZ_H2;             // ~35 MB
static_assert(OFF_DOWNO + SZ_DOWNO <= OFF_UOG, "downo overlay must end before persistent tail");

// ---------------- single merged converter ----------------
// flat grid 12544:
// [0,1024) x hi/lo | [1024,2432) Uog | [2432,3840) Uou | [3840,5888) Uod |
// [5888,6400) wr transpose hi/lo (+cnt/done zero) | [6400,12544) U_in transposes
__global__ __launch_bounds__(256) void k_cvt(
    const float* __restrict__ x,   const float* __restrict__ Uog,
    const float* __restrict__ Uou, const float* __restrict__ Uod,
    const float* __restrict__ wr,
    const float* __restrict__ Uig, const float* __restrict__ Uiu, const float* __restrict__ Uid,
    f16* __restrict__ xh, f16* __restrict__ xl,
    f16* __restrict__ uog, f16* __restrict__ uou, f16* __restrict__ uod,
    f16* __restrict__ wh, f16* __restrict__ wl,
    f16* __restrict__ ig, f16* __restrict__ iu, f16* __restrict__ idn,
    int* __restrict__ cnt, int* __restrict__ done){
  __shared__ float tile[32][33];
  const int b = blockIdx.x, tid = threadIdx.x;
  if(b < 1024){   // x: hi + lo planes (router needs split-f16)
    const size_t i = (size_t)b*256 + tid;
    float4 v = ld4(x + i*4);
    f16x4 H, L;
    H[0]=(f16)v.x; L[0]=(f16)(v.x-(float)H[0]);
    H[1]=(f16)v.y; L[1]=(f16)(v.y-(float)H[1]);
    H[2]=(f16)v.z; L[2]=(f16)(v.z-(float)H[2]);
    H[3]=(f16)v.w; L[3]=(f16)(v.w-(float)H[3]);
    *reinterpret_cast<f16x4*>(xh + i*4) = H;
    *reinterpret_cast<f16x4*>(xl + i*4) = L;
    return;
  }
  if(b < 5888){
    const float* in; f16* hi; size_t i;
    if(b < 2432){        in = Uog; hi = uog; i = (size_t)(b-1024)*256 + tid; }
    else if(b < 3840){   in = Uou; hi = uou; i = (size_t)(b-2432)*256 + tid; }
    else {               in = Uod; hi = uod; i = (size_t)(b-3840)*256 + tid; }
    float4 v = ld4(in + i*4);
    f16x4 H;
    H[0]=(f16)(v.x*16.f); H[1]=(f16)(v.y*16.f); H[2]=(f16)(v.z*16.f); H[3]=(f16)(v.w*16.f);
    *reinterpret_cast<f16x4*>(hi + i*4) = H;
    return;
  }
  if(b < 6400){
    // wr transpose: [2048][256] -> [256][2048] hi/lo (x16). 512 blocks
    const int wb = b - 5888;
    if(wb == 0){ cnt[tid] = 0; if(tid == 0) done[0] = 0; }
    const int c0 = (wb & 7)*32, r0 = (wb >> 3)*32;
    { const int r = tid>>3, c4 = (tid&7)*4;
      float4 v = ld4(wr + (size_t)(r0+r)*NEXP + c0 + c4);
      tile[r][c4]=v.x; tile[r][c4+1]=v.y; tile[r][c4+2]=v.z; tile[r][c4+3]=v.w; }
    __syncthreads();
    { const int c = tid>>3, r4 = (tid&7)*4;
      f16x4 H, L;
      #pragma unroll
      for(int k = 0; k < 4; k++){
        float v = tile[r4+k][c]*16.f;
        H[k] = (f16)v; L[k] = (f16)(v - (float)H[k]);
      }
      const size_t o = (size_t)(c0+c)*HID + r0 + r4;
      *reinterpret_cast<f16x4*>(wh + o) = H;
      *reinterpret_cast<f16x4*>(wl + o) = L; }
    return;
  }
  // U_in transposes: [G][R][128] -> [G][128][R] (x16)
  const int b2 = b - 6400;
  const int cx = b2 & 3, ry = (b2>>2) & 63, z = b2 >> 8;
  const int tensor = z >> 3, g = z & 7;
  const float* in; f16* o; int R;
  if(tensor == 0){ in = Uig; o = ig; R = HID; }
  else if(tensor == 1){ in = Uiu; o = iu; R = HID; }
  else { in = Uid; o = idn; R = IDIM; }
  const int r0 = ry*32, c0 = cx*32;
  if(r0 >= R) return;
  in += (size_t)g*R*RNK; o += (size_t)g*RNK*R;
  { const int r = tid>>3, c4 = (tid&7)*4;
    float4 v = ld4(in + (size_t)(r0+r)*RNK + c0 + c4);
    tile[r][c4]=v.x; tile[r][c4+1]=v.y; tile[r][c4+2]=v.z; tile[r][c4+3]=v.w; }
  __syncthreads();
  { const int c = tid>>3, r4 = (tid&7)*4;
    f16x4 H;
    #pragma unroll
    for(int k = 0; k < 4; k++) H[k] = (f16)(tile[r4+k][c]*16.f);
    *reinterpret_cast<f16x4*>(o + (size_t)(c0+c)*R + r0 + r4) = H; }
}

// ---------------- router MFMA, split-f16 3-pass, fp32-class accuracy ----------------
__global__ __launch_bounds__(256) void k_router_mfma(
    const f16* __restrict__ xh, const f16* __restrict__ xl,
    const f16* __restrict__ wh, const f16* __restrict__ wl,
    float* __restrict__ lpart){
  __shared__ float red[4][32][64];
  const int m = blockIdx.x, ecol = blockIdx.y, kz = blockIdx.z;
  const int tid = threadIdx.x;
  const int wid = tid>>6, lane = tid&63, q = lane>>4, id = lane&15;
  const int r0 = m*32, e0 = ecol*64;
  const int kb = kz*512 + wid*128;
  f32x4 acc[2][4];
  #pragma unroll
  for(int f = 0; f < 2; f++)
    #pragma unroll
    for(int c = 0; c < 4; c++) acc[f][c] = (f32x4){0.f,0.f,0.f,0.f};
  #pragma unroll
  for(int kk = 0; kk < 128; kk += 32){
    const size_t a0 = (size_t)(r0+id)*HID    + kb + kk + q*8;
    const size_t a1 = (size_t)(r0+16+id)*HID + kb + kk + q*8;
    f16x8 ah0 = ldh8(xh + a0), al0 = ldh8(xl + a0);
    f16x8 ah1 = ldh8(xh + a1), al1 = ldh8(xl + a1);
    #pragma unroll
    for(int c = 0; c < 4; c++){
      const size_t bo = (size_t)(e0 + c*16 + id)*HID + kb + kk + q*8;
      f16x8 bh = ldh8(wh + bo);
      f16x8 bl = ldh8(wl + bo);
      acc[0][c] = MFMA16(ah0, bh, acc[0][c]);
      acc[0][c] = MFMA16(ah0, bl, acc[0][c]);
      acc[0][c] = MFMA16(al0, bh, acc[0][c]);
      acc[1][c] = MFMA16(ah1, bh, acc[1][c]);
      acc[1][c] = MFMA16(ah1, bl, acc[1][c]);
      acc[1][c] = MFMA16(al1, bh, acc[1][c]);
    }
  }
  #pragma unroll
  for(int f = 0; f < 2; f++)
    #pragma unroll
    for(int c = 0; c < 4; c++)
      #pragma unroll
      for(int r = 0; r < 4; r++)
        red[wid][f*16 + q*4 + r][c*16 + id] = acc[f][c][r];
  __syncthreads();
  const int row = tid>>3, c8 = (tid&7)*8;
  float o[8];
  #pragma unroll
  for(int j = 0; j < 8; j++)
    o[j] = (red[0][row][c8+j] + red[1][row][c8+j] + red[2][row][c8+j] + red[3][row][c8+j])*0.0625f;
  float* dst = &lpart[((size_t)kz*TNUM + r0 + row)*NEXP + e0 + c8];
  st4(dst,     make_float4(o[0],o[1],o[2],o[3]));
  st4(dst + 4, make_float4(o[4],o[5],o[6],o[7]));
}

// ---------------- fused top-6 + meta/scatter (last-block-done pattern) ----------------
__global__ __launch_bounds__(256) void k_topk_meta(
    const float* __restrict__ lpart,
    int* __restrict__ sel, float* __restrict__ wt, int* __restrict__ cnt,
    int* __restrict__ done,
    int* __restrict__ estart, int* __restrict__ tile_group, int* __restrict__ hdr,
    int* __restrict__ row_t, int* __restrict__ pos_of_pair){
  __shared__ float wv[4];
  __shared__ int   wi[4];
  __shared__ float swin[KTOP];
  __shared__ int   iwin[KTOP];
  __shared__ int   lastflag;
  __shared__ int scnt[256];
  __shared__ int gsum[8];
  __shared__ int g0[9];
  __shared__ int curs[256];
  const int t = blockIdx.x, tid = threadIdx.x;
  const int lane = tid & 63, wid = tid >> 6;
  const size_t base = (size_t)t*NEXP + tid;
  float v = lpart[base] + lpart[base + (size_t)TNUM*NEXP]
          + lpart[base + (size_t)2*TNUM*NEXP] + lpart[base + (size_t)3*TNUM*NEXP];
  for(int k = 0; k < KTOP; k++){
    float cv = v; int ci = tid;
    #pragma unroll
    for(int off = 1; off < 64; off <<= 1){
      float ov = __shfl_xor(cv, off);
      int   oi = __shfl_xor(ci, off);
      if(ov > cv || (ov == cv && oi < ci)){ cv = ov; ci = oi; }
    }
    if(lane == 0){ wv[wid] = cv; wi[wid] = ci; }
    __syncthreads();
    if(tid == 0){
      float bv = wv[0]; int bi = wi[0];
      #pragma unroll
      for(int w2 = 1; w2 < 4; w2++)
        if(wv[w2] > bv || (wv[w2] == bv && wi[w2] < bi)){ bv = wv[w2]; bi = wi[w2]; }
      swin[k] = bv; iwin[k] = bi;
    }
    __syncthreads();
    if(tid == iwin[k]) v = -INFINITY;
  }
  if(tid == 0){
    float mx = swin[0], s = 0.f, ww[KTOP];
    #pragma unroll
    for(int k = 0; k < KTOP; k++){ ww[k] = expf(swin[k]-mx); s += ww[k]; }
    float inv = 1.f/s;
    #pragma unroll
    for(int k = 0; k < KTOP; k++){
      sel[t*KTOP+k] = iwin[k];
      wt[t*KTOP+k]  = ww[k]*inv;
      atomicAdd(&cnt[iwin[k]], 1);
    }
    __threadfence();                         // publish sel/wt/cnt at device scope
    const int old = atomicAdd(done, 1);
    lastflag = (old == TNUM-1) ? 1 : 0;
  }
  __syncthreads();
  if(!lastflag) return;
  __threadfence();                           // acquire-side fence before reading others' data
  // ---- meta + scatter (runs in exactly one block; identical result whichever it is) ----
  scnt[tid] = cnt[tid];
  if(tid < 8) gsum[tid] = 0;
  __syncthreads();
  atomicAdd(&gsum[tid>>5], scnt[tid]);
  __syncthreads();
  if(tid == 0){
    int run = 0;
    for(int g = 0; g < 8; g++){ g0[g] = run; run += (gsum[g]+31) & ~31; }
    g0[8] = run; hdr[0] = run>>5; hdr[1] = run;
  }
  __syncthreads();
  int g = tid >> 5, s = g0[g];
  for(int i = (g<<5); i < tid; i++) s += scnt[i];
  estart[tid] = s; curs[tid] = s;
  const int nt = g0[8] >> 5;
  for(int t2 = tid; t2 < MAXTILES; t2 += 256){
    int gg = -1;
    if(t2 < nt){
      for(int g2 = 0; g2 < 8; g2++) if(t2*32 >= g0[g2] && t2*32 < g0[g2+1]) gg = g2;
    }
    tile_group[t2] = gg;
  }
  __syncthreads();
  for(int p = tid; p < NPAIR; p += 256){
    const int e = sel[p];
    const int pos = atomicAdd(&curs[e], 1);
    row_t[pos] = p / KTOP;
    pos_of_pair[p] = pos;
  }
}

// ---------------- stage1 MFMA v3: grid (32 nt, 16 m), B-sharing blocks co-locate per XCD ----------------
__global__ __launch_bounds__(256) void k_mm_stage1(
    const f16* __restrict__ xh,
    const f16* __restrict__ Bg_, const f16* __restrict__ Bu_,
    f16* __restrict__ H1){
  __shared__ float red[4][32][64];
  const int nt = blockIdx.x, m = blockIdx.y;
  const int pu = nt>>4, g = (nt>>1)&7, ch = nt&1;
  const f16* B = (pu ? Bu_ : Bg_) + (size_t)g*RNK*HID + (size_t)ch*64*HID;
  const int tid = threadIdx.x;
  const int wid = tid>>6, lane = tid&63, q = lane>>4, id = lane&15;
  const int kb = wid*512;
  const int r0 = m*32;
  f32x4 acc[2][4];
  #pragma unroll
  for(int f = 0; f < 2; f++)
    #pragma unroll
    for(int c = 0; c < 4; c++) acc[f][c] = (f32x4){0.f,0.f,0.f,0.f};
  #pragma unroll 4
  for(int kk = 0; kk < 512; kk += 32){
    f16x8 a0 = ldh8(xh + (size_t)(r0+id)*HID    + kb + kk + q*8);
    f16x8 a1 = ldh8(xh + (size_t)(r0+16+id)*HID + kb + kk + q*8);
    #pragma unroll
    for(int c = 0; c < 4; c++){
      f16x8 b = ldh8(B + (size_t)(c*16+id)*HID + kb + kk + q*8);
      acc[0][c] = MFMA16(a0, b, acc[0][c]);
      acc[1][c] = MFMA16(a1, b, acc[1][c]);
    }
  }
  #pragma unroll
  for(int f = 0; f < 2; f++)
    #pragma unroll
    for(int c = 0; c < 4; c++)
      #pragma unroll
      for(int r = 0; r < 4; r++)
        red[wid][f*16 + q*4 + r][c*16 + id] = acc[f][c][r];
  __syncthreads();
  f16* out = H1 + (size_t)pu*TNUM*(NGRP*RNK);
  const int row = tid>>3, c8 = (tid&7)*8;
  f16x8 o8;
  #pragma unroll
  for(int j = 0; j < 8; j++)
    o8[j] = (f16)(red[0][row][c8+j] + red[1][row][c8+j] + red[2][row][c8+j] + red[3][row][c8+j]);
  *reinterpret_cast<f16x8*>(&out[(size_t)(r0+row)*(NGRP*RNK) + g*RNK + ch*64 + c8]) = o8;
}

// ---------------- core2 MFMA with in-kernel fp32->f16 transpose of the core ----------------
__global__ __launch_bounds__(256) void k_core2(
    const float* __restrict__ Cg, const float* __restrict__ Cu,
    const f16* __restrict__ H1,
    const int* __restrict__ estart, const int* __restrict__ cnt,
    const int* __restrict__ row_t,
    f16* __restrict__ h2g, f16* __restrict__ h2u){
  __shared__ f16 Cs[RNK][RNK+8];
  __shared__ float tile[32][33];
  const int e = blockIdx.x, up = blockIdx.y;
  const int n = cnt[e];
  if(n == 0) return;
  const float* Cf = (up ? Cu : Cg) + (size_t)e*RNK*RNK;
  const int tid = threadIdx.x;
  #pragma unroll 2
  for(int st = 0; st < 16; st++){
    const int R0 = (st>>2)*32, C0 = (st&3)*32;
    { const int r = tid>>3, c4 = (tid&7)*4;
      float4 v = ld4(Cf + (size_t)(R0+r)*RNK + C0 + c4);
      tile[r][c4]=v.x; tile[r][c4+1]=v.y; tile[r][c4+2]=v.z; tile[r][c4+3]=v.w; }
    __syncthreads();
    { const int c = tid>>3, r4 = (tid&7)*4;
      f16x4 H;
      #pragma unroll
      for(int k2 = 0; k2 < 4; k2++) H[k2] = (f16)(tile[r4+k2][c]*16.f);
      *reinterpret_cast<f16x4*>(&Cs[C0+c][R0+r4]) = H; }
    __syncthreads();
  }
  const int j0 = estart[e], g = e >> 5;
  const f16* A = H1 + (size_t)up*TNUM*(NGRP*RNK);
  f16* o = up ? h2u : h2g;
  const int wid = tid>>6, lane = tid&63, q = lane>>4, id = lane&15;
  for(int rt = 0; rt*16 < n; rt++){
    const int jrow = j0 + rt*16 + id;
    const int jj = jrow < j0+n ? jrow : j0;
    const f16* arow = A + (size_t)row_t[jj]*(NGRP*RNK) + g*RNK;
    f32x4 acc0 = (f32x4){0.f,0.f,0.f,0.f};
    f32x4 acc1 = (f32x4){0.f,0.f,0.f,0.f};
    #pragma unroll
    for(int kk = 0; kk < RNK; kk += 32){
      f16x8 a = ldh8(arow + kk + q*8);
      f16x8 b0 = *reinterpret_cast<const f16x8*>(&Cs[wid*32 + id][kk + q*8]);
      f16x8 b1 = *reinterpret_cast<const f16x8*>(&Cs[wid*32 + 16 + id][kk + q*8]);
      acc0 = MFMA16(a, b0, acc0);
      acc1 = MFMA16(a, b1, acc1);
    }
    #pragma unroll
    for(int r = 0; r < 4; r++){
      const int j = j0 + rt*16 + q*4 + r;
      if(j < j0+n){
        o[(size_t)j*RNK + wid*32 + id]      = (f16)acc0[r];
        o[(size_t)j*RNK + wid*32 + 16 + id] = (f16)acc1[r];
      }
    }
  }
}

// ---------------- fused gateup + down_in ----------------
// grid (MAXTILES, 4 K-quarters); block: 32 rows, 352 inter cols in LDS, then d1 partial
__global__ __launch_bounds__(256) void k_gateup_downin(
    const f16* __restrict__ Ag, const f16* __restrict__ Au,
    const f16* __restrict__ Bg, const f16* __restrict__ Bu,
    const f16* __restrict__ Bd,
    const int* __restrict__ tg,
    f16* __restrict__ d1p){
  __shared__ f16 inter_s[32][360];   // 352 cols + 8 pad (stride 720 B, 16B-aligned)
  const int g = tg[blockIdx.x];
  if(g < 0) return;
  const int j0 = blockIdx.x*32, qz = blockIdx.y;
  const int cbase = qz*352;
  const int tid = threadIdx.x, wid = tid>>6, lane = tid&63, q = lane>>4, id = lane&15;
  const size_t bbase = (size_t)g*IDIM*RNK;
  // hoist A fragments (h2 rows j0..j0+31, full K=128, both planes) -> 16 f16x8 regs
  f16x8 aG[2][4], aU[2][4];
  #pragma unroll
  for(int f = 0; f < 2; f++)
    #pragma unroll
    for(int k4 = 0; k4 < 4; k4++){
      const size_t off = (size_t)(j0 + f*16 + id)*RNK + k4*32 + q*8;
      aG[f][k4] = ldh8(Ag + off);
      aU[f][k4] = ldh8(Au + off);
    }
  // phase 1: inter_s = silu(gate)*up for cols [cbase, cbase+352)
  for(int t = wid; t < 22; t += 4){
    const int c0 = cbase + t*16;
    f32x4 accg0 = (f32x4){0.f,0.f,0.f,0.f}, accg1 = (f32x4){0.f,0.f,0.f,0.f};
    f32x4 accu0 = (f32x4){0.f,0.f,0.f,0.f}, accu1 = (f32x4){0.f,0.f,0.f,0.f};
    #pragma unroll
    for(int k4 = 0; k4 < 4; k4++){
      const size_t bo = bbase + (size_t)(c0 + id)*RNK + k4*32 + q*8;
      f16x8 bg = ldh8(Bg + bo);
      f16x8 bu = ldh8(Bu + bo);
      accg0 = MFMA16(aG[0][k4], bg, accg0);
      accg1 = MFMA16(aG[1][k4], bg, accg1);
      accu0 = MFMA16(aU[0][k4], bu, accu0);
      accu1 = MFMA16(aU[1][k4], bu, accu1);
    }
    #pragma unroll
    for(int r = 0; r < 4; r++){
      float vg0 = accg0[r]*(1.f/4096.f), vu0 = accu0[r]*(1.f/4096.f);
      float vg1 = accg1[r]*(1.f/4096.f), vu1 = accu1[r]*(1.f/4096.f);
      inter_s[q*4+r][t*16+id]    = (f16)(vg0/(1.f+expf(-vg0))*vu0*256.f);
      inter_s[16+q*4+r][t*16+id] = (f16)(vg1/(1.f+expf(-vg1))*vu1*256.f);
    }
  }
  __syncthreads();
  // phase 2: d1 partial = inter_s @ Bd[K slice]; wave w -> cols [w*32, w*32+32)
  const int col0 = wid*32;
  f32x4 acc[2][2];
  #pragma unroll
  for(int f = 0; f < 2; f++)
    #pragma unroll
    for(int c = 0; c < 2; c++) acc[f][c] = (f32x4){0.f,0.f,0.f,0.f};
  const f16* Bdg = Bd + (size_t)g*RNK*IDIM;
  #pragma unroll 2
  for(int kk = 0; kk < 352; kk += 32){
    f16x8 a0 = *reinterpret_cast<const f16x8*>(&inter_s[id][kk + q*8]);
    f16x8 a1 = *reinterpret_cast<const f16x8*>(&inter_s[16+id][kk + q*8]);
    #pragma unroll
    for(int c = 0; c < 2; c++){
      f16x8 b = ldh8(Bdg + (size_t)(col0 + c*16 + id)*IDIM + cbase + kk + q*8);
      acc[0][c] = MFMA16(a0, b, acc[0][c]);
      acc[1][c] = MFMA16(a1, b, acc[1][c]);
    }
  }
  f16* out = d1p + (size_t)qz*NRCAP*RNK;
  #pragma unroll
  for(int f = 0; f < 2; f++)
    #pragma unroll
    for(int c = 0; c < 2; c++)
      #pragma unroll
      for(int r = 0; r < 4; r++)
        out[(size_t)(j0 + f*16 + q*4 + r)*RNK + col0 + c*16 + id] = (f16)acc[f][c][r];
}

// ---------------- core_down MFMA: sums 4 f16 d1 partials; in-kernel core transpose ----------------
__global__ __launch_bounds__(256) void k_core_down(
    const float* __restrict__ Cd,
    const f16* __restrict__ d1p,
    const int* __restrict__ estart, const int* __restrict__ cnt,
    f16* __restrict__ d2){
  __shared__ f16 Cs[RNK][RNK+8];
  __shared__ float tile[32][33];
  const int e = blockIdx.x;
  const int n = cnt[e];
  if(n == 0) return;
  const float* Cf = Cd + (size_t)e*RNK*RNK;
  const int tid = threadIdx.x;
  #pragma unroll 2
  for(int st = 0; st < 16; st++){
    const int R0 = (st>>2)*32, C0 = (st&3)*32;
    { const int r = tid>>3, c4 = (tid&7)*4;
      float4 v = ld4(Cf + (size_t)(R0+r)*RNK + C0 + c4);
      tile[r][c4]=v.x; tile[r][c4+1]=v.y; tile[r][c4+2]=v.z; tile[r][c4+3]=v.w; }
    __syncthreads();
    { const int c = tid>>3, r4 = (tid&7)*4;
      f16x4 H;
      #pragma unroll
      for(int k2 = 0; k2 < 4; k2++) H[k2] = (f16)(tile[r4+k2][c]*16.f);
      *reinterpret_cast<f16x4*>(&Cs[C0+c][R0+r4]) = H; }
    __syncthreads();
  }
  const int j0 = estart[e];
  const size_t PL = (size_t)NRCAP*RNK;
  const int wid = tid>>6, lane = tid&63, q = lane>>4, id = lane&15;
  for(int rt = 0; rt*16 < n; rt++){
    const int jrow = j0 + rt*16 + id;
    const int jj = jrow < j0+n ? jrow : j0;
    const size_t arow = (size_t)jj*RNK;
    f32x4 acc0 = (f32x4){0.f,0.f,0.f,0.f};
    f32x4 acc1 = (f32x4){0.f,0.f,0.f,0.f};
    #pragma unroll
    for(int kk = 0; kk < RNK; kk += 32){
      const size_t off = arow + kk + q*8;
      f16x8 a = ldh8(d1p + off);
      a += ldh8(d1p + off + PL);
      a += ldh8(d1p + off + 2*PL);
      a += ldh8(d1p + off + 3*PL);
      f16x8 b0 = *reinterpret_cast<const f16x8*>(&Cs[wid*32 + id][kk + q*8]);
      f16x8 b1 = *reinterpret_cast<const f16x8*>(&Cs[wid*32 + 16 + id][kk + q*8]);
      acc0 = MFMA16(a, b0, acc0);
      acc1 = MFMA16(a, b1, acc1);
    }
    #pragma unroll
    for(int r = 0; r < 4; r++){
      const int j = j0 + rt*16 + q*4 + r;
      if(j < j0+n){
        d2[(size_t)j*RNK + wid*32 + id]      = (f16)acc0[r];
        d2[(size_t)j*RNK + wid*32 + 16 + id] = (f16)acc1[r];
      }
    }
  }
}

// ---------------- down_out MFMA: writes f16 downo at x2^10 scale ----------------
__global__ __launch_bounds__(128) void k_mm_down_out(
    const f16* __restrict__ A_, const f16* __restrict__ B_,
    const int* __restrict__ tg,
    f16* __restrict__ downo){
  const int g = tg[blockIdx.x];
  if(g < 0) return;
  const int j0 = blockIdx.x*32;
  const f16* B = B_ + (size_t)g*HID*RNK;
  const int tid = threadIdx.x;
  const int wid = tid>>6, lane = tid&63, q = lane>>4, id = lane&15;
  const int c0 = blockIdx.y*128 + wid*64;
  f32x4 acc[2][4];
  #pragma unroll
  for(int f = 0; f < 2; f++)
    #pragma unroll
    for(int c = 0; c < 4; c++) acc[f][c] = (f32x4){0.f,0.f,0.f,0.f};
  #pragma unroll 2
  for(int kk = 0; kk < RNK; kk += 32){
    f16x8 a0 = ldh8(A_ + (size_t)(j0+id)*RNK    + kk + q*8);
    f16x8 a1 = ldh8(A_ + (size_t)(j0+16+id)*RNK + kk + q*8);
    #pragma unroll
    for(int c = 0; c < 4; c++){
      f16x8 b = ldh8(B + (size_t)(c0 + c*16 + id)*RNK + kk + q*8);
      acc[0][c] = MFMA16(a0, b, acc[0][c]);
      acc[1][c] = MFMA16(a1, b, acc[1][c]);
    }
  }
  #pragma unroll
  for(int f = 0; f < 2; f++)
    #pragma unroll
    for(int c = 0; c < 4; c++)
      #pragma unroll
      for(int r = 0; r < 4; r++)
        downo[(size_t)(j0 + f*16 + q*4 + r)*HID + c0 + c*16 + id] = (f16)(acc[f][c][r]*(1.f/1024.f));
}

// ---------------- combine: out[t] = sum_k wt/1024 * downo16[pos(t,k)] ----------------
__global__ __launch_bounds__(256) void k_combine(const f16* __restrict__ downo,
                                                 const int* __restrict__ pos_of_pair,
                                                 const float* __restrict__ wt,
                                                 float* __restrict__ out){
  const int idx = blockIdx.x*256 + threadIdx.x;      // 0..262143
  const int t  = idx >> 9;
  const int h4 = (idx & 511) << 2;
  float4 acc = make_float4(0.f,0.f,0.f,0.f);
  #pragma unroll
  for(int k = 0; k < KTOP; k++){
    const int p = t*KTOP + k;
    const float w = wt[p]*(1.f/1024.f);
    const int pos = pos_of_pair[p];
    f16x4 v = *reinterpret_cast<const f16x4*>(&downo[(size_t)pos*HID + h4]);
    acc.x += w*(float)v[0]; acc.y += w*(float)v[1];
    acc.z += w*(float)v[2]; acc.w += w*(float)v[3];
  }
  st4(&out[(size_t)t*HID + h4], acc);
}

extern "C" void kernel_launch(void* const* d_in, const int* in_sizes, int n_in,
                              void* d_out, int out_size, void* d_ws, size_t ws_size,
                              hipStream_t stream){
  const float* x   = (const float*)d_in[0];
  const float* wr  = (const float*)d_in[1];
  const float* Uig = (const float*)d_in[2];
  const float* cg  = (const float*)d_in[3];
  const float* Uog = (const float*)d_in[4];
  const float* Uiu = (const float*)d_in[5];
  const float* cu  = (const float*)d_in[6];
  const float* Uou = (const float*)d_in[7];
  const float* Uid = (const float*)d_in[8];
  const float* cd  = (const float*)d_in[9];
  const float* Uod = (const float*)d_in[10];
  float* out = (float*)d_out;
  char* ws = (char*)d_ws;
  if(ws_size < WS_NEED) return;   // insufficient scratch — fail visibly

  int*   sel    = (int*)  (ws + OFF_SEL);
  float* wt     = (float*)(ws + OFF_WT);
  int*   cnt    = (int*)  (ws + OFF_CNT);
  int*   estart = (int*)  (ws + OFF_ESTART);
  int*   tg     = (int*)  (ws + OFF_TG);
  int*   hdr    = (int*)  (ws + OFF_HDR);
  int*   done   = (int*)  (ws + OFF_DONE);
  int*   row_t  = (int*)  (ws + OFF_ROWT);
  int*   pos    = (int*)  (ws + OFF_POS);
  float* lpart  = (float*)(ws + OFF_LPART);
  f16* xh    = (f16*)(ws + OFF_XH);
  f16* xl    = (f16*)(ws + OFF_XL);
  f16* utig  = (f16*)(ws + OFF_UTIG);
  f16* utiu  = (f16*)(ws + OFF_UTIU);
  f16* H1    = (f16*)(ws + OFF_H1);
  f16* uog   = (f16*)(ws + OFF_UOG);
  f16* uou   = (f16*)(ws + OFF_UOU);
  f16* utid  = (f16*)(ws + OFF_UTID);
  f16* uod   = (f16*)(ws + OFF_UOD);
  f16* wrh   = (f16*)(ws + OFF_WRH);
  f16* wrl   = (f16*)(ws + OFF_WRL);
  f16* h2g   = (f16*)(ws + OFF_H2G);
  f16* h2u   = (f16*)(ws + OFF_H2U);
  f16* d1p   = (f16*)(ws + OFF_D1P);
  f16* d2    = (f16*)(ws + OFF_D2);
  f16* downo = (f16*)(ws + OFF_DOWNO);

  // one merged conversion kernel (also zeroes cnt + done)
  k_cvt      <<<12544,             256, 0, stream>>>(x, Uog, Uou, Uod, wr, Uig, Uiu, Uid,
                                                     xh, xl, uog, uou, uod, wrh, wrl,
                                                     utig, utiu, utid, cnt, done);

  // routing chain (lpart overlays H1, dead before stage1)
  k_router_mfma<<<dim3(16,4,4),    256, 0, stream>>>(xh, xl, wrh, wrl, lpart);
  k_topk_meta<<<TNUM,              256, 0, stream>>>(lpart, sel, wt, cnt, done,
                                                     estart, tg, hdr, row_t, pos);

  k_mm_stage1<<<dim3(32,16),       256, 0, stream>>>(xh, utig, utiu, H1);
  k_core2    <<<dim3(NEXP,2),      256, 0, stream>>>(cg, cu, H1, estart, cnt, row_t, h2g, h2u);
  k_gateup_downin<<<dim3(MAXTILES,4),256,0, stream>>>(h2g, h2u, uog, uou, utid, tg, d1p);
  k_core_down<<<NEXP,              256, 0, stream>>>(cd, d1p, estart, cnt, d2);
  k_mm_down_out<<<dim3(MAXTILES,16),128,0, stream>>>(d2, uod, tg, downo);
  k_combine  <<<1024,              256, 0, stream>>>(downo, pos, wt, out);
}

// Round 14
// 136.561 us; speedup vs baseline: 1.0993x; 1.0530x over previous
//
#include <hip/hip_runtime.h>
#include <cmath>
#include <cstdint>

#define TNUM 512
#define HID 2048
#define NEXP 256
#define NGRP 8
#define KTOP 6
#define IDIM 1408
#define RNK 128
#define NPAIR (TNUM*KTOP)          // 3072
#define NRCAP 3328                 // 3072 + 8*32 padding capacity
#define MAXTILES (NRCAP/32)        // 104

typedef _Float16 f16;
typedef f16  f16x8 __attribute__((ext_vector_type(8)));
typedef f16  f16x4 __attribute__((ext_vector_type(4)));
typedef float f32x4 __attribute__((ext_vector_type(4)));
#define MFMA16(a,b,c) __builtin_amdgcn_mfma_f32_16x16x32_f16((a),(b),(c),0,0,0)

static __device__ __forceinline__ float4 ld4(const float* p){ return *reinterpret_cast<const float4*>(p); }
static __device__ __forceinline__ void st4(float* p, float4 v){ *reinterpret_cast<float4*>(p) = v; }
static __device__ __forceinline__ f16x8 ldh8(const f16* p){ return *reinterpret_cast<const f16x8*>(p); }

// ---------------- workspace layout (~35 MB with overlays) ----------------
constexpr size_t A256(size_t x){ return (x + 255) & ~(size_t)255; }
constexpr size_t OFF_SEL    = 0;
constexpr size_t OFF_WT     = A256(OFF_SEL    + (size_t)NPAIR*4);
constexpr size_t OFF_CNT    = A256(OFF_WT     + (size_t)NPAIR*4);
constexpr size_t OFF_ESTART = A256(OFF_CNT    + (size_t)NEXP*4);
constexpr size_t OFF_TG     = A256(OFF_ESTART + (size_t)NEXP*4);
constexpr size_t OFF_HDR    = A256(OFF_TG     + (size_t)MAXTILES*4);
constexpr size_t OFF_ROWT   = A256(OFF_HDR    + 16);
constexpr size_t OFF_POS    = A256(OFF_ROWT   + (size_t)NRCAP*4);
constexpr size_t OFF_BIG    = A256(OFF_POS    + (size_t)NPAIR*4);

constexpr size_t SZ_XH    = (size_t)TNUM*HID*2;            // 2 MB
constexpr size_t SZ_UTI   = (size_t)NGRP*RNK*HID*2;        // 4 MB
constexpr size_t SZ_H1ALL = (size_t)2*TNUM*NGRP*RNK*2;     // 2 MB
constexpr size_t SZ_UO    = (size_t)NGRP*IDIM*RNK*2;       // 2.88 MB
constexpr size_t SZ_UOD   = (size_t)NGRP*HID*RNK*2;        // 4 MB
constexpr size_t SZ_WR    = (size_t)NEXP*HID*2;            // 1 MB
constexpr size_t SZ_H2    = (size_t)NRCAP*RNK*2;           // 0.85 MB
constexpr size_t SZ_DOWNO = (size_t)NRCAP*HID*2;           // 13.6 MB (f16)

// overlay region: [xh|xl|utig|utiu|H1] = 14 MB; downo f16 (13.6) overlays it; lpart overlays H1
constexpr size_t OFF_XH    = OFF_BIG;
constexpr size_t OFF_XL    = OFF_XH   + SZ_XH;
constexpr size_t OFF_UTIG  = OFF_XL   + SZ_XH;
constexpr size_t OFF_UTIU  = OFF_UTIG + SZ_UTI;
constexpr size_t OFF_H1    = OFF_UTIU + SZ_UTI;            // f16 [2][T][G*RNK]
constexpr size_t REG_END   = OFF_H1   + SZ_H1ALL;
constexpr size_t OFF_DOWNO = OFF_XH;                       // lives down_out->combine (f16)
constexpr size_t OFF_LPART = OFF_H1;                       // 2 MB, dead before stage1
// persistent tail
constexpr size_t OFF_UOG   = REG_END;
constexpr size_t OFF_UOU   = OFF_UOG  + SZ_UO;
constexpr size_t OFF_UTID  = OFF_UOU  + SZ_UO;
constexpr size_t OFF_UOD   = OFF_UTID + SZ_UO;
constexpr size_t OFF_WRH   = OFF_UOD  + SZ_UOD;
constexpr size_t OFF_WRL   = OFF_WRH  + SZ_WR;
constexpr size_t OFF_H2G   = OFF_WRL  + SZ_WR;
constexpr size_t OFF_H2U   = OFF_H2G  + SZ_H2;
constexpr size_t OFF_D1P   = OFF_H2U  + SZ_H2;             // 4 f16 partial planes
constexpr size_t OFF_D2    = OFF_D1P  + 4*SZ_H2;
constexpr size_t WS_NEED   = OFF_D2   + SZ_H2;             // ~35 MB
static_assert(OFF_DOWNO + SZ_DOWNO <= OFF_UOG, "downo overlay must end before persistent tail");

// ---------------- single merged converter ----------------
// flat grid 12544:
// [0,1024) x hi/lo | [1024,2432) Uog | [2432,3840) Uou | [3840,5888) Uod |
// [5888,6400) wr transpose hi/lo (+cnt zero) | [6400,12544) U_in transposes
__global__ __launch_bounds__(256) void k_cvt(
    const float* __restrict__ x,   const float* __restrict__ Uog,
    const float* __restrict__ Uou, const float* __restrict__ Uod,
    const float* __restrict__ wr,
    const float* __restrict__ Uig, const float* __restrict__ Uiu, const float* __restrict__ Uid,
    f16* __restrict__ xh, f16* __restrict__ xl,
    f16* __restrict__ uog, f16* __restrict__ uou, f16* __restrict__ uod,
    f16* __restrict__ wh, f16* __restrict__ wl,
    f16* __restrict__ ig, f16* __restrict__ iu, f16* __restrict__ idn,
    int* __restrict__ cnt){
  __shared__ float tile[32][33];
  const int b = blockIdx.x, tid = threadIdx.x;
  if(b < 1024){   // x: hi + lo planes (router needs split-f16)
    const size_t i = (size_t)b*256 + tid;
    float4 v = ld4(x + i*4);
    f16x4 H, L;
    H[0]=(f16)v.x; L[0]=(f16)(v.x-(float)H[0]);
    H[1]=(f16)v.y; L[1]=(f16)(v.y-(float)H[1]);
    H[2]=(f16)v.z; L[2]=(f16)(v.z-(float)H[2]);
    H[3]=(f16)v.w; L[3]=(f16)(v.w-(float)H[3]);
    *reinterpret_cast<f16x4*>(xh + i*4) = H;
    *reinterpret_cast<f16x4*>(xl + i*4) = L;
    return;
  }
  if(b < 5888){
    const float* in; f16* hi; size_t i;
    if(b < 2432){        in = Uog; hi = uog; i = (size_t)(b-1024)*256 + tid; }
    else if(b < 3840){   in = Uou; hi = uou; i = (size_t)(b-2432)*256 + tid; }
    else {               in = Uod; hi = uod; i = (size_t)(b-3840)*256 + tid; }
    float4 v = ld4(in + i*4);
    f16x4 H;
    H[0]=(f16)(v.x*16.f); H[1]=(f16)(v.y*16.f); H[2]=(f16)(v.z*16.f); H[3]=(f16)(v.w*16.f);
    *reinterpret_cast<f16x4*>(hi + i*4) = H;
    return;
  }
  if(b < 6400){
    // wr transpose: [2048][256] -> [256][2048] hi/lo (x16). 512 blocks
    const int wb = b - 5888;
    if(wb == 0) cnt[tid] = 0;
    const int c0 = (wb & 7)*32, r0 = (wb >> 3)*32;
    { const int r = tid>>3, c4 = (tid&7)*4;
      float4 v = ld4(wr + (size_t)(r0+r)*NEXP + c0 + c4);
      tile[r][c4]=v.x; tile[r][c4+1]=v.y; tile[r][c4+2]=v.z; tile[r][c4+3]=v.w; }
    __syncthreads();
    { const int c = tid>>3, r4 = (tid&7)*4;
      f16x4 H, L;
      #pragma unroll
      for(int k = 0; k < 4; k++){
        float v = tile[r4+k][c]*16.f;
        H[k] = (f16)v; L[k] = (f16)(v - (float)H[k]);
      }
      const size_t o = (size_t)(c0+c)*HID + r0 + r4;
      *reinterpret_cast<f16x4*>(wh + o) = H;
      *reinterpret_cast<f16x4*>(wl + o) = L; }
    return;
  }
  // U_in transposes: [G][R][128] -> [G][128][R] (x16)
  const int b2 = b - 6400;
  const int cx = b2 & 3, ry = (b2>>2) & 63, z = b2 >> 8;
  const int tensor = z >> 3, g = z & 7;
  const float* in; f16* o; int R;
  if(tensor == 0){ in = Uig; o = ig; R = HID; }
  else if(tensor == 1){ in = Uiu; o = iu; R = HID; }
  else { in = Uid; o = idn; R = IDIM; }
  const int r0 = ry*32, c0 = cx*32;
  if(r0 >= R) return;
  in += (size_t)g*R*RNK; o += (size_t)g*RNK*R;
  { const int r = tid>>3, c4 = (tid&7)*4;
    float4 v = ld4(in + (size_t)(r0+r)*RNK + c0 + c4);
    tile[r][c4]=v.x; tile[r][c4+1]=v.y; tile[r][c4+2]=v.z; tile[r][c4+3]=v.w; }
  __syncthreads();
  { const int c = tid>>3, r4 = (tid&7)*4;
    f16x4 H;
    #pragma unroll
    for(int k = 0; k < 4; k++) H[k] = (f16)(tile[r4+k][c]*16.f);
    *reinterpret_cast<f16x4*>(o + (size_t)(c0+c)*R + r0 + r4) = H; }
}

// ---------------- router MFMA, split-f16 3-pass, fp32-class accuracy ----------------
__global__ __launch_bounds__(256) void k_router_mfma(
    const f16* __restrict__ xh, const f16* __restrict__ xl,
    const f16* __restrict__ wh, const f16* __restrict__ wl,
    float* __restrict__ lpart){
  __shared__ float red[4][32][64];
  const int m = blockIdx.x, ecol = blockIdx.y, kz = blockIdx.z;
  const int tid = threadIdx.x;
  const int wid = tid>>6, lane = tid&63, q = lane>>4, id = lane&15;
  const int r0 = m*32, e0 = ecol*64;
  const int kb = kz*512 + wid*128;
  f32x4 acc[2][4];
  #pragma unroll
  for(int f = 0; f < 2; f++)
    #pragma unroll
    for(int c = 0; c < 4; c++) acc[f][c] = (f32x4){0.f,0.f,0.f,0.f};
  #pragma unroll
  for(int kk = 0; kk < 128; kk += 32){
    const size_t a0 = (size_t)(r0+id)*HID    + kb + kk + q*8;
    const size_t a1 = (size_t)(r0+16+id)*HID + kb + kk + q*8;
    f16x8 ah0 = ldh8(xh + a0), al0 = ldh8(xl + a0);
    f16x8 ah1 = ldh8(xh + a1), al1 = ldh8(xl + a1);
    #pragma unroll
    for(int c = 0; c < 4; c++){
      const size_t bo = (size_t)(e0 + c*16 + id)*HID + kb + kk + q*8;
      f16x8 bh = ldh8(wh + bo);
      f16x8 bl = ldh8(wl + bo);
      acc[0][c] = MFMA16(ah0, bh, acc[0][c]);
      acc[0][c] = MFMA16(ah0, bl, acc[0][c]);
      acc[0][c] = MFMA16(al0, bh, acc[0][c]);
      acc[1][c] = MFMA16(ah1, bh, acc[1][c]);
      acc[1][c] = MFMA16(ah1, bl, acc[1][c]);
      acc[1][c] = MFMA16(al1, bh, acc[1][c]);
    }
  }
  #pragma unroll
  for(int f = 0; f < 2; f++)
    #pragma unroll
    for(int c = 0; c < 4; c++)
      #pragma unroll
      for(int r = 0; r < 4; r++)
        red[wid][f*16 + q*4 + r][c*16 + id] = acc[f][c][r];
  __syncthreads();
  const int row = tid>>3, c8 = (tid&7)*8;
  float o[8];
  #pragma unroll
  for(int j = 0; j < 8; j++)
    o[j] = (red[0][row][c8+j] + red[1][row][c8+j] + red[2][row][c8+j] + red[3][row][c8+j])*0.0625f;
  float* dst = &lpart[((size_t)kz*TNUM + r0 + row)*NEXP + e0 + c8];
  st4(dst,     make_float4(o[0],o[1],o[2],o[3]));
  st4(dst + 4, make_float4(o[4],o[5],o[6],o[7]));
}

// ---------------- per-token top-6 (wave-parallel argmax) ----------------
__global__ __launch_bounds__(256) void k_topk(const float* __restrict__ lpart,
                                              int* __restrict__ sel,
                                              float* __restrict__ wt,
                                              int* __restrict__ cnt){
  __shared__ float wv[4];
  __shared__ int   wi[4];
  __shared__ float swin[KTOP];
  __shared__ int   iwin[KTOP];
  const int t = blockIdx.x, tid = threadIdx.x;
  const int lane = tid & 63, wid = tid >> 6;
  const size_t base = (size_t)t*NEXP + tid;
  float v = lpart[base] + lpart[base + (size_t)TNUM*NEXP]
          + lpart[base + (size_t)2*TNUM*NEXP] + lpart[base + (size_t)3*TNUM*NEXP];
  for(int k = 0; k < KTOP; k++){
    float cv = v; int ci = tid;
    #pragma unroll
    for(int off = 1; off < 64; off <<= 1){
      float ov = __shfl_xor(cv, off);
      int   oi = __shfl_xor(ci, off);
      if(ov > cv || (ov == cv && oi < ci)){ cv = ov; ci = oi; }
    }
    if(lane == 0){ wv[wid] = cv; wi[wid] = ci; }
    __syncthreads();
    if(tid == 0){
      float bv = wv[0]; int bi = wi[0];
      #pragma unroll
      for(int w2 = 1; w2 < 4; w2++)
        if(wv[w2] > bv || (wv[w2] == bv && wi[w2] < bi)){ bv = wv[w2]; bi = wi[w2]; }
      swin[k] = bv; iwin[k] = bi;
    }
    __syncthreads();
    if(tid == iwin[k]) v = -INFINITY;
  }
  if(tid == 0){
    float mx = swin[0], s = 0.f, ww[KTOP];
    #pragma unroll
    for(int k = 0; k < KTOP; k++){ ww[k] = expf(swin[k]-mx); s += ww[k]; }
    float inv = 1.f/s;
    #pragma unroll
    for(int k = 0; k < KTOP; k++){
      sel[t*KTOP+k] = iwin[k];
      wt[t*KTOP+k]  = ww[k]*inv;
      atomicAdd(&cnt[iwin[k]], 1);
    }
  }
}

// ---------------- meta + scatter (single block, LDS cursors) ----------------
__global__ __launch_bounds__(256) void k_meta_scatter(
    const int* __restrict__ cnt, const int* __restrict__ sel,
    int* __restrict__ estart, int* __restrict__ tile_group, int* __restrict__ hdr,
    int* __restrict__ row_t, int* __restrict__ pos_of_pair){
  __shared__ int scnt[256];
  __shared__ int gsum[8];
  __shared__ int g0[9];
  __shared__ int curs[256];
  const int tid = threadIdx.x;
  scnt[tid] = cnt[tid];
  if(tid < 8) gsum[tid] = 0;
  __syncthreads();
  atomicAdd(&gsum[tid>>5], scnt[tid]);
  __syncthreads();
  if(tid == 0){
    int run = 0;
    for(int g = 0; g < 8; g++){ g0[g] = run; run += (gsum[g]+31) & ~31; }
    g0[8] = run; hdr[0] = run>>5; hdr[1] = run;
  }
  __syncthreads();
  int g = tid >> 5, s = g0[g];
  for(int i = (g<<5); i < tid; i++) s += scnt[i];
  estart[tid] = s; curs[tid] = s;
  const int nt = g0[8] >> 5;
  for(int t2 = tid; t2 < MAXTILES; t2 += 256){
    int gg = -1;
    if(t2 < nt){
      for(int g2 = 0; g2 < 8; g2++) if(t2*32 >= g0[g2] && t2*32 < g0[g2+1]) gg = g2;
    }
    tile_group[t2] = gg;
  }
  __syncthreads();
  for(int p = tid; p < NPAIR; p += 256){
    const int e = sel[p];
    const int pos = atomicAdd(&curs[e], 1);
    row_t[pos] = p / KTOP;
    pos_of_pair[p] = pos;
  }
}

// ---------------- stage1 MFMA v3: grid (32 nt, 16 m), B-sharing blocks co-locate per XCD ----------------
__global__ __launch_bounds__(256) void k_mm_stage1(
    const f16* __restrict__ xh,
    const f16* __restrict__ Bg_, const f16* __restrict__ Bu_,
    f16* __restrict__ H1){
  __shared__ float red[4][32][64];
  const int nt = blockIdx.x, m = blockIdx.y;
  const int pu = nt>>4, g = (nt>>1)&7, ch = nt&1;
  const f16* B = (pu ? Bu_ : Bg_) + (size_t)g*RNK*HID + (size_t)ch*64*HID;
  const int tid = threadIdx.x;
  const int wid = tid>>6, lane = tid&63, q = lane>>4, id = lane&15;
  const int kb = wid*512;
  const int r0 = m*32;
  f32x4 acc[2][4];
  #pragma unroll
  for(int f = 0; f < 2; f++)
    #pragma unroll
    for(int c = 0; c < 4; c++) acc[f][c] = (f32x4){0.f,0.f,0.f,0.f};
  #pragma unroll 4
  for(int kk = 0; kk < 512; kk += 32){
    f16x8 a0 = ldh8(xh + (size_t)(r0+id)*HID    + kb + kk + q*8);
    f16x8 a1 = ldh8(xh + (size_t)(r0+16+id)*HID + kb + kk + q*8);
    #pragma unroll
    for(int c = 0; c < 4; c++){
      f16x8 b = ldh8(B + (size_t)(c*16+id)*HID + kb + kk + q*8);
      acc[0][c] = MFMA16(a0, b, acc[0][c]);
      acc[1][c] = MFMA16(a1, b, acc[1][c]);
    }
  }
  #pragma unroll
  for(int f = 0; f < 2; f++)
    #pragma unroll
    for(int c = 0; c < 4; c++)
      #pragma unroll
      for(int r = 0; r < 4; r++)
        red[wid][f*16 + q*4 + r][c*16 + id] = acc[f][c][r];
  __syncthreads();
  f16* out = H1 + (size_t)pu*TNUM*(NGRP*RNK);
  const int row = tid>>3, c8 = (tid&7)*8;
  f16x8 o8;
  #pragma unroll
  for(int j = 0; j < 8; j++)
    o8[j] = (f16)(red[0][row][c8+j] + red[1][row][c8+j] + red[2][row][c8+j] + red[3][row][c8+j]);
  *reinterpret_cast<f16x8*>(&out[(size_t)(r0+row)*(NGRP*RNK) + g*RNK + ch*64 + c8]) = o8;
}

// ---------------- core2 MFMA with in-kernel fp32->f16 transpose of the core ----------------
__global__ __launch_bounds__(256) void k_core2(
    const float* __restrict__ Cg, const float* __restrict__ Cu,
    const f16* __restrict__ H1,
    const int* __restrict__ estart, const int* __restrict__ cnt,
    const int* __restrict__ row_t,
    f16* __restrict__ h2g, f16* __restrict__ h2u){
  __shared__ f16 Cs[RNK][RNK+8];
  __shared__ float tile[32][33];
  const int e = blockIdx.x, up = blockIdx.y;
  const int n = cnt[e];
  if(n == 0) return;
  const float* Cf = (up ? Cu : Cg) + (size_t)e*RNK*RNK;
  const int tid = threadIdx.x;
  #pragma unroll 2
  for(int st = 0; st < 16; st++){
    const int R0 = (st>>2)*32, C0 = (st&3)*32;
    { const int r = tid>>3, c4 = (tid&7)*4;
      float4 v = ld4(Cf + (size_t)(R0+r)*RNK + C0 + c4);
      tile[r][c4]=v.x; tile[r][c4+1]=v.y; tile[r][c4+2]=v.z; tile[r][c4+3]=v.w; }
    __syncthreads();
    { const int c = tid>>3, r4 = (tid&7)*4;
      f16x4 H;
      #pragma unroll
      for(int k2 = 0; k2 < 4; k2++) H[k2] = (f16)(tile[r4+k2][c]*16.f);
      *reinterpret_cast<f16x4*>(&Cs[C0+c][R0+r4]) = H; }
    __syncthreads();
  }
  const int j0 = estart[e], g = e >> 5;
  const f16* A = H1 + (size_t)up*TNUM*(NGRP*RNK);
  f16* o = up ? h2u : h2g;
  const int wid = tid>>6, lane = tid&63, q = lane>>4, id = lane&15;
  for(int rt = 0; rt*16 < n; rt++){
    const int jrow = j0 + rt*16 + id;
    const int jj = jrow < j0+n ? jrow : j0;
    const f16* arow = A + (size_t)row_t[jj]*(NGRP*RNK) + g*RNK;
    f32x4 acc0 = (f32x4){0.f,0.f,0.f,0.f};
    f32x4 acc1 = (f32x4){0.f,0.f,0.f,0.f};
    #pragma unroll
    for(int kk = 0; kk < RNK; kk += 32){
      f16x8 a = ldh8(arow + kk + q*8);
      f16x8 b0 = *reinterpret_cast<const f16x8*>(&Cs[wid*32 + id][kk + q*8]);
      f16x8 b1 = *reinterpret_cast<const f16x8*>(&Cs[wid*32 + 16 + id][kk + q*8]);
      acc0 = MFMA16(a, b0, acc0);
      acc1 = MFMA16(a, b1, acc1);
    }
    #pragma unroll
    for(int r = 0; r < 4; r++){
      const int j = j0 + rt*16 + q*4 + r;
      if(j < j0+n){
        o[(size_t)j*RNK + wid*32 + id]      = (f16)acc0[r];
        o[(size_t)j*RNK + wid*32 + 16 + id] = (f16)acc1[r];
      }
    }
  }
}

// ---------------- fused gateup + down_in ----------------
// grid (MAXTILES, 4 K-quarters); block: 32 rows, 352 inter cols in LDS, then d1 partial
__global__ __launch_bounds__(256) void k_gateup_downin(
    const f16* __restrict__ Ag, const f16* __restrict__ Au,
    const f16* __restrict__ Bg, const f16* __restrict__ Bu,
    const f16* __restrict__ Bd,
    const int* __restrict__ tg,
    f16* __restrict__ d1p){
  __shared__ f16 inter_s[32][360];   // 352 cols + 8 pad (stride 720 B, 16B-aligned)
  const int g = tg[blockIdx.x];
  if(g < 0) return;
  const int j0 = blockIdx.x*32, qz = blockIdx.y;
  const int cbase = qz*352;
  const int tid = threadIdx.x, wid = tid>>6, lane = tid&63, q = lane>>4, id = lane&15;
  const size_t bbase = (size_t)g*IDIM*RNK;
  // hoist A fragments (h2 rows j0..j0+31, full K=128, both planes) -> 16 f16x8 regs
  f16x8 aG[2][4], aU[2][4];
  #pragma unroll
  for(int f = 0; f < 2; f++)
    #pragma unroll
    for(int k4 = 0; k4 < 4; k4++){
      const size_t off = (size_t)(j0 + f*16 + id)*RNK + k4*32 + q*8;
      aG[f][k4] = ldh8(Ag + off);
      aU[f][k4] = ldh8(Au + off);
    }
  // phase 1: inter_s = silu(gate)*up for cols [cbase, cbase+352)
  for(int t = wid; t < 22; t += 4){
    const int c0 = cbase + t*16;
    f32x4 accg0 = (f32x4){0.f,0.f,0.f,0.f}, accg1 = (f32x4){0.f,0.f,0.f,0.f};
    f32x4 accu0 = (f32x4){0.f,0.f,0.f,0.f}, accu1 = (f32x4){0.f,0.f,0.f,0.f};
    #pragma unroll
    for(int k4 = 0; k4 < 4; k4++){
      const size_t bo = bbase + (size_t)(c0 + id)*RNK + k4*32 + q*8;
      f16x8 bg = ldh8(Bg + bo);
      f16x8 bu = ldh8(Bu + bo);
      accg0 = MFMA16(aG[0][k4], bg, accg0);
      accg1 = MFMA16(aG[1][k4], bg, accg1);
      accu0 = MFMA16(aU[0][k4], bu, accu0);
      accu1 = MFMA16(aU[1][k4], bu, accu1);
    }
    #pragma unroll
    for(int r = 0; r < 4; r++){
      float vg0 = accg0[r]*(1.f/4096.f), vu0 = accu0[r]*(1.f/4096.f);
      float vg1 = accg1[r]*(1.f/4096.f), vu1 = accu1[r]*(1.f/4096.f);
      inter_s[q*4+r][t*16+id]    = (f16)(vg0/(1.f+expf(-vg0))*vu0*256.f);
      inter_s[16+q*4+r][t*16+id] = (f16)(vg1/(1.f+expf(-vg1))*vu1*256.f);
    }
  }
  __syncthreads();
  // phase 2: d1 partial = inter_s @ Bd[K slice]; wave w -> cols [w*32, w*32+32)
  const int col0 = wid*32;
  f32x4 acc[2][2];
  #pragma unroll
  for(int f = 0; f < 2; f++)
    #pragma unroll
    for(int c = 0; c < 2; c++) acc[f][c] = (f32x4){0.f,0.f,0.f,0.f};
  const f16* Bdg = Bd + (size_t)g*RNK*IDIM;
  #pragma unroll 2
  for(int kk = 0; kk < 352; kk += 32){
    f16x8 a0 = *reinterpret_cast<const f16x8*>(&inter_s[id][kk + q*8]);
    f16x8 a1 = *reinterpret_cast<const f16x8*>(&inter_s[16+id][kk + q*8]);
    #pragma unroll
    for(int c = 0; c < 2; c++){
      f16x8 b = ldh8(Bdg + (size_t)(col0 + c*16 + id)*IDIM + cbase + kk + q*8);
      acc[0][c] = MFMA16(a0, b, acc[0][c]);
      acc[1][c] = MFMA16(a1, b, acc[1][c]);
    }
  }
  f16* out = d1p + (size_t)qz*NRCAP*RNK;
  #pragma unroll
  for(int f = 0; f < 2; f++)
    #pragma unroll
    for(int c = 0; c < 2; c++)
      #pragma unroll
      for(int r = 0; r < 4; r++)
        out[(size_t)(j0 + f*16 + q*4 + r)*RNK + col0 + c*16 + id] = (f16)acc[f][c][r];
}

// ---------------- core_down MFMA: sums 4 f16 d1 partials; in-kernel core transpose ----------------
__global__ __launch_bounds__(256) void k_core_down(
    const float* __restrict__ Cd,
    const f16* __restrict__ d1p,
    const int* __restrict__ estart, const int* __restrict__ cnt,
    f16* __restrict__ d2){
  __shared__ f16 Cs[RNK][RNK+8];
  __shared__ float tile[32][33];
  const int e = blockIdx.x;
  const int n = cnt[e];
  if(n == 0) return;
  const float* Cf = Cd + (size_t)e*RNK*RNK;
  const int tid = threadIdx.x;
  #pragma unroll 2
  for(int st = 0; st < 16; st++){
    const int R0 = (st>>2)*32, C0 = (st&3)*32;
    { const int r = tid>>3, c4 = (tid&7)*4;
      float4 v = ld4(Cf + (size_t)(R0+r)*RNK + C0 + c4);
      tile[r][c4]=v.x; tile[r][c4+1]=v.y; tile[r][c4+2]=v.z; tile[r][c4+3]=v.w; }
    __syncthreads();
    { const int c = tid>>3, r4 = (tid&7)*4;
      f16x4 H;
      #pragma unroll
      for(int k2 = 0; k2 < 4; k2++) H[k2] = (f16)(tile[r4+k2][c]*16.f);
      *reinterpret_cast<f16x4*>(&Cs[C0+c][R0+r4]) = H; }
    __syncthreads();
  }
  const int j0 = estart[e];
  const size_t PL = (size_t)NRCAP*RNK;
  const int wid = tid>>6, lane = tid&63, q = lane>>4, id = lane&15;
  for(int rt = 0; rt*16 < n; rt++){
    const int jrow = j0 + rt*16 + id;
    const int jj = jrow < j0+n ? jrow : j0;
    const size_t arow = (size_t)jj*RNK;
    f32x4 acc0 = (f32x4){0.f,0.f,0.f,0.f};
    f32x4 acc1 = (f32x4){0.f,0.f,0.f,0.f};
    #pragma unroll
    for(int kk = 0; kk < RNK; kk += 32){
      const size_t off = arow + kk + q*8;
      f16x8 a = ldh8(d1p + off);
      a += ldh8(d1p + off + PL);
      a += ldh8(d1p + off + 2*PL);
      a += ldh8(d1p + off + 3*PL);
      f16x8 b0 = *reinterpret_cast<const f16x8*>(&Cs[wid*32 + id][kk + q*8]);
      f16x8 b1 = *reinterpret_cast<const f16x8*>(&Cs[wid*32 + 16 + id][kk + q*8]);
      acc0 = MFMA16(a, b0, acc0);
      acc1 = MFMA16(a, b1, acc1);
    }
    #pragma unroll
    for(int r = 0; r < 4; r++){
      const int j = j0 + rt*16 + q*4 + r;
      if(j < j0+n){
        d2[(size_t)j*RNK + wid*32 + id]      = (f16)acc0[r];
        d2[(size_t)j*RNK + wid*32 + 16 + id] = (f16)acc1[r];
      }
    }
  }
}

// ---------------- down_out MFMA: writes f16 downo at x2^10 scale ----------------
__global__ __launch_bounds__(128) void k_mm_down_out(
    const f16* __restrict__ A_, const f16* __restrict__ B_,
    const int* __restrict__ tg,
    f16* __restrict__ downo){
  const int g = tg[blockIdx.x];
  if(g < 0) return;
  const int j0 = blockIdx.x*32;
  const f16* B = B_ + (size_t)g*HID*RNK;
  const int tid = threadIdx.x;
  const int wid = tid>>6, lane = tid&63, q = lane>>4, id = lane&15;
  const int c0 = blockIdx.y*128 + wid*64;
  f32x4 acc[2][4];
  #pragma unroll
  for(int f = 0; f < 2; f++)
    #pragma unroll
    for(int c = 0; c < 4; c++) acc[f][c] = (f32x4){0.f,0.f,0.f,0.f};
  #pragma unroll 2
  for(int kk = 0; kk < RNK; kk += 32){
    f16x8 a0 = ldh8(A_ + (size_t)(j0+id)*RNK    + kk + q*8);
    f16x8 a1 = ldh8(A_ + (size_t)(j0+16+id)*RNK + kk + q*8);
    #pragma unroll
    for(int c = 0; c < 4; c++){
      f16x8 b = ldh8(B + (size_t)(c0 + c*16 + id)*RNK + kk + q*8);
      acc[0][c] = MFMA16(a0, b, acc[0][c]);
      acc[1][c] = MFMA16(a1, b, acc[1][c]);
    }
  }
  #pragma unroll
  for(int f = 0; f < 2; f++)
    #pragma unroll
    for(int c = 0; c < 4; c++)
      #pragma unroll
      for(int r = 0; r < 4; r++)
        downo[(size_t)(j0 + f*16 + q*4 + r)*HID + c0 + c*16 + id] = (f16)(acc[f][c][r]*(1.f/1024.f));
}

// ---------------- combine: out[t] = sum_k wt/1024 * downo16[pos(t,k)] ----------------
__global__ __launch_bounds__(256) void k_combine(const f16* __restrict__ downo,
                                                 const int* __restrict__ pos_of_pair,
                                                 const float* __restrict__ wt,
                                                 float* __restrict__ out){
  const int idx = blockIdx.x*256 + threadIdx.x;      // 0..262143
  const int t  = idx >> 9;
  const int h4 = (idx & 511) << 2;
  float4 acc = make_float4(0.f,0.f,0.f,0.f);
  #pragma unroll
  for(int k = 0; k < KTOP; k++){
    const int p = t*KTOP + k;
    const float w = wt[p]*(1.f/1024.f);
    const int pos = pos_of_pair[p];
    f16x4 v = *reinterpret_cast<const f16x4*>(&downo[(size_t)pos*HID + h4]);
    acc.x += w*(float)v[0]; acc.y += w*(float)v[1];
    acc.z += w*(float)v[2]; acc.w += w*(float)v[3];
  }
  st4(&out[(size_t)t*HID + h4], acc);
}

extern "C" void kernel_launch(void* const* d_in, const int* in_sizes, int n_in,
                              void* d_out, int out_size, void* d_ws, size_t ws_size,
                              hipStream_t stream){
  const float* x   = (const float*)d_in[0];
  const float* wr  = (const float*)d_in[1];
  const float* Uig = (const float*)d_in[2];
  const float* cg  = (const float*)d_in[3];
  const float* Uog = (const float*)d_in[4];
  const float* Uiu = (const float*)d_in[5];
  const float* cu  = (const float*)d_in[6];
  const float* Uou = (const float*)d_in[7];
  const float* Uid = (const float*)d_in[8];
  const float* cd  = (const float*)d_in[9];
  const float* Uod = (const float*)d_in[10];
  float* out = (float*)d_out;
  char* ws = (char*)d_ws;
  if(ws_size < WS_NEED) return;   // insufficient scratch — fail visibly

  int*   sel    = (int*)  (ws + OFF_SEL);
  float* wt     = (float*)(ws + OFF_WT);
  int*   cnt    = (int*)  (ws + OFF_CNT);
  int*   estart = (int*)  (ws + OFF_ESTART);
  int*   tg     = (int*)  (ws + OFF_TG);
  int*   hdr    = (int*)  (ws + OFF_HDR);
  int*   row_t  = (int*)  (ws + OFF_ROWT);
  int*   pos    = (int*)  (ws + OFF_POS);
  float* lpart  = (float*)(ws + OFF_LPART);
  f16* xh    = (f16*)(ws + OFF_XH);
  f16* xl    = (f16*)(ws + OFF_XL);
  f16* utig  = (f16*)(ws + OFF_UTIG);
  f16* utiu  = (f16*)(ws + OFF_UTIU);
  f16* H1    = (f16*)(ws + OFF_H1);
  f16* uog   = (f16*)(ws + OFF_UOG);
  f16* uou   = (f16*)(ws + OFF_UOU);
  f16* utid  = (f16*)(ws + OFF_UTID);
  f16* uod   = (f16*)(ws + OFF_UOD);
  f16* wrh   = (f16*)(ws + OFF_WRH);
  f16* wrl   = (f16*)(ws + OFF_WRL);
  f16* h2g   = (f16*)(ws + OFF_H2G);
  f16* h2u   = (f16*)(ws + OFF_H2U);
  f16* d1p   = (f16*)(ws + OFF_D1P);
  f16* d2    = (f16*)(ws + OFF_D2);
  f16* downo = (f16*)(ws + OFF_DOWNO);

  // one merged conversion kernel (also zeroes cnt)
  k_cvt      <<<12544,             256, 0, stream>>>(x, Uog, Uou, Uod, wr, Uig, Uiu, Uid,
                                                     xh, xl, uog, uou, uod, wrh, wrl,
                                                     utig, utiu, utid, cnt);

  // routing chain (lpart overlays H1, dead before stage1)
  k_router_mfma<<<dim3(16,4,4),    256, 0, stream>>>(xh, xl, wrh, wrl, lpart);
  k_topk     <<<TNUM,              256, 0, stream>>>(lpart, sel, wt, cnt);
  k_meta_scatter<<<1,              256, 0, stream>>>(cnt, sel, estart, tg, hdr, row_t, pos);

  k_mm_stage1<<<dim3(32,16),       256, 0, stream>>>(xh, utig, utiu, H1);
  k_core2    <<<dim3(NEXP,2),      256, 0, stream>>>(cg, cu, H1, estart, cnt, row_t, h2g, h2u);
  k_gateup_downin<<<dim3(MAXTILES,4),256,0, stream>>>(h2g, h2u, uog, uou, utid, tg, d1p);
  k_core_down<<<NEXP,              256, 0, stream>>>(cd, d1p, estart, cnt, d2);
  k_mm_down_out<<<dim3(MAXTILES,16),128,0, stream>>>(d2, uod, tg, downo);
  k_combine  <<<1024,              256, 0, stream>>>(downo, pos, wt, out);
}